// Round 9
// baseline (329.946 us; speedup 1.0000x reference)
//
#include <hip/hip_runtime.h>
#include <hip/hip_bf16.h>
#include <math.h>

#define ND 128
#define NH 8
#define DKK 16
#define NT 3
#define NR 4
#define NB 8
#define NMAT 12   // pack: 0=Q, 1..4=K@att[r], 5=V(type1), 6..9=V@msg[r], 10=A, 11=s2u
#define SCB 4096  // scan elems per block (256 threads x 16)

typedef unsigned short ushort_t;
typedef __bf16 bf16_t;
typedef bf16_t bf16x8 __attribute__((ext_vector_type(8)));
typedef float f32x4 __attribute__((ext_vector_type(4)));

__device__ __forceinline__ float bf2f(unsigned short u) {
    union { unsigned int i; float f; } v; v.i = ((unsigned int)u) << 16; return v.f;
}
__device__ __forceinline__ unsigned short f2bf(float f) {
    union { float f; unsigned int i; } v; v.f = f;
    unsigned int x = v.i;
    unsigned int lsb = (x >> 16) & 1u;
    x += 0x7fffu + lsb;
    return (unsigned short)(x >> 16);
}
__device__ __forceinline__ unsigned int pk2(float a, float b) {
    return (unsigned int)f2bf(a) | ((unsigned int)f2bf(b) << 16);
}
__device__ __forceinline__ void load_bf8(const ushort_t* p, float* o) {
    uint4 u = *reinterpret_cast<const uint4*>(p);
    o[0]=bf2f(u.x & 0xffff); o[1]=bf2f(u.x >> 16);
    o[2]=bf2f(u.y & 0xffff); o[3]=bf2f(u.y >> 16);
    o[4]=bf2f(u.z & 0xffff); o[5]=bf2f(u.z >> 16);
    o[6]=bf2f(u.w & 0xffff); o[7]=bf2f(u.w >> 16);
}
__device__ __forceinline__ bf16x8 as_bf16x8(uint4 u) {
    union { uint4 u; bf16x8 v; } c; c.u = u; return c.v;
}

// ---------------- sort / bucket infrastructure ----------------

__global__ void k_zero(int n, int* offs, int* winner) {
    int i = blockIdx.x * 256 + threadIdx.x;
    if (i < n) { offs[i] = 0; winner[i] = -1; }
}

// standalone edge counting (tier-B / fallback); tier-A fuses this into k_fuse.
__global__ void k_count(int e, const int* src, const int* tgt, const int* etype,
                        int* cnts, int* winner, int* rank) {
    int i = blockIdx.x * 256 + threadIdx.x;
    if (i < e) {
        rank[i] = atomicAdd(&cnts[tgt[i]], 1);
        if (etype[i] == 0) atomicMax(&winner[src[i]], i);  // last-write-wins == max id
    }
}

// ---- node-partition scans (depend ONLY on node_type; edge-independent) ----

__global__ void k_nscanA(int n, const int* ntype, int* nb4) {
    __shared__ int tr[256][3];
    int b = blockIdx.x, tid = threadIdx.x;
    int base = b * SCB + tid * 16;
    int c0 = 0, c1 = 0, c2 = 0;
    #pragma unroll
    for (int i = 0; i < 16; i++) {
        int idx = base + i;
        if (idx < n) {
            int t = ntype[idx];
            c0 += (t == 0); c1 += (t == 1); c2 += (t == 2);
        }
    }
    tr[tid][0] = c0; tr[tid][1] = c1; tr[tid][2] = c2;
    __syncthreads();
    for (int d = 128; d > 0; d >>= 1) {
        if (tid < d) {
            tr[tid][0] += tr[tid + d][0];
            tr[tid][1] += tr[tid + d][1];
            tr[tid][2] += tr[tid + d][2];
        }
        __syncthreads();
    }
    if (tid == 0) {
        nb4[b * 4]     = tr[0][0];
        nb4[b * 4 + 1] = tr[0][1];
        nb4[b * 4 + 2] = tr[0][2];
    }
}

__global__ void k_nscanB(int nb, const int* nb4, int* nboff4, int* tcnt, int* tstart) {
    if (threadIdx.x == 0) {
        int r0 = 0, r1 = 0, r2 = 0;
        for (int b = 0; b < nb; b++) {
            nboff4[b * 4]     = r0;
            nboff4[b * 4 + 1] = r1;
            nboff4[b * 4 + 2] = r2;
            r0 += nb4[b * 4];
            r1 += nb4[b * 4 + 1];
            r2 += nb4[b * 4 + 2];
        }
        tcnt[0] = r0; tcnt[1] = r1; tcnt[2] = r2;
        tstart[0] = 0; tstart[1] = r0; tstart[2] = r0 + r1;
    }
}

// order -> STABLE type partition (ascending node id within each type segment)
__global__ void k_nscanC(int n, const int* ntype, const int* nboff4,
                         const int* tstart, int* order) {
    __shared__ int tr[256][3];
    int b = blockIdx.x, tid = threadIdx.x;
    int base = b * SCB + tid * 16;
    signed char ty[16];
    int c0 = 0, c1 = 0, c2 = 0;
    #pragma unroll
    for (int i = 0; i < 16; i++) {
        int idx = base + i;
        int t = (idx < n) ? ntype[idx] : -1;
        ty[i] = (signed char)t;
        c0 += (t == 0); c1 += (t == 1); c2 += (t == 2);
    }
    tr[tid][0] = c0; tr[tid][1] = c1; tr[tid][2] = c2;
    __syncthreads();
    for (int d = 1; d < 256; d <<= 1) {
        int w0 = (tid >= d) ? tr[tid - d][0] : 0;
        int w1 = (tid >= d) ? tr[tid - d][1] : 0;
        int w2 = (tid >= d) ? tr[tid - d][2] : 0;
        __syncthreads();
        tr[tid][0] += w0; tr[tid][1] += w1; tr[tid][2] += w2;
        __syncthreads();
    }
    int p0 = tstart[0] + nboff4[b * 4]     + tr[tid][0] - c0;
    int p1 = tstart[1] + nboff4[b * 4 + 1] + tr[tid][1] - c1;
    int p2 = tstart[2] + nboff4[b * 4 + 2] + tr[tid][2] - c2;
    #pragma unroll
    for (int i = 0; i < 16; i++) {
        int idx = base + i;
        if (idx < n) {
            int t = ty[i];
            if (t == 0)      order[p0++] = idx;
            else if (t == 1) order[p1++] = idx;
            else             order[p2++] = idx;
        }
    }
}

// ---- offs scans (depend on edge counts; run after counting) ----

__global__ void k_oscanA(int n, const int* offs, int* ob) {
    __shared__ int red[256];
    int b = blockIdx.x, tid = threadIdx.x;
    int base = b * SCB + tid * 16;
    int s = 0;
    #pragma unroll
    for (int i = 0; i < 16; i++) {
        int idx = base + i;
        if (idx < n) s += offs[idx];
    }
    red[tid] = s;
    __syncthreads();
    for (int d = 128; d > 0; d >>= 1) {
        if (tid < d) red[tid] += red[tid + d];
        __syncthreads();
    }
    if (tid == 0) ob[b] = red[0];
}

__global__ void k_oscanB(int nb, const int* ob, int* oboff) {
    if (threadIdx.x == 0) {
        int run = 0;
        for (int b = 0; b < nb; b++) { oboff[b] = run; run += ob[b]; }
    }
}

__global__ void k_oscanC(int n, int* offs, const int* oboff) {
    __shared__ int red[256];
    int b = blockIdx.x, tid = threadIdx.x;
    int base = b * SCB + tid * 16;
    int v[16];
    int s = 0;
    #pragma unroll
    for (int i = 0; i < 16; i++) {
        int idx = base + i;
        v[i] = (idx < n) ? offs[idx] : 0;
        s += v[i];
    }
    red[tid] = s;
    __syncthreads();
    for (int d = 1; d < 256; d <<= 1) {
        int vv = (tid >= d) ? red[tid - d] : 0;
        __syncthreads();
        red[tid] += vv;
        __syncthreads();
    }
    int run = oboff[b] + red[tid] - s;   // exclusive prefix
    #pragma unroll
    for (int i = 0; i < 16; i++) {
        int idx = base + i;
        if (idx < n) { offs[idx] = run; run += v[i]; }
    }
    if (base <= n && n < base + 16) offs[n] = run;   // grand total
}

// ATOMIC-FREE edge scatter: slot = scanned offs + precomputed rank.
// mode=1: eord[p] = (src*NR+etype) | ntype[src]<<28 ; mode=0: eord[p] = edge id
__global__ void k_scatter(int e, const int* src, const int* tgt, const int* etype,
                          const int* ntype, const int* offs, const int* rank,
                          int* eord, int mode) {
    int i = blockIdx.x * 256 + threadIdx.x;
    if (i < e) {
        int p = offs[tgt[i]] + rank[i];
        if (mode) {
            int s = src[i];
            eord[p] = (s * NR + etype[i]) | (ntype[s] << 28);
        } else {
            eord[p] = i;
        }
    }
}

// ================= PACK (12 mats, proven) =================

__global__ void k_pack(const float* Qw, const float* Qb, const float* Kw, const float* Kb,
                       const float* Vw, const float* Vb, const float* Aw, const float* Ab,
                       const float* s2u, const float* r_att, const float* r_msg,
                       ushort_t* Wall, float* bcat) {
    int blk = blockIdx.x;
    int kb = blk & 3;
    int c = (blk >> 2) & 7;
    int tm = blk >> 5;
    int m = tm % NMAT, t = tm / NMAT;
    int lane = threadIdx.x;
    int nn = c * 16 + (lane & 15);
    int quad = lane >> 4;
    int k0 = kb * 32 + quad * 8;
    ushort_t* dst = Wall + (size_t)blk * 512 + lane * 8;

    if (m == 0 || m == 5 || m == 10 || m == 11) {
        const float* W; const float* B;
        if (m == 0)       { W = Qw + (size_t)t * ND * ND; B = Qb + t * ND; }
        else if (m == 5)  { W = Vw + (size_t)ND * ND;     B = Vb + ND; }
        else if (m == 10) { W = Aw + (size_t)t * ND * ND; B = Ab + t * ND; }
        else              { W = s2u;                      B = nullptr; }
        #pragma unroll
        for (int j = 0; j < 8; j++) dst[j] = f2bf(W[(size_t)(k0 + j) * ND + nn]);
        if (kb == 0 && quad == 0)
            bcat[(t * NMAT + m) * ND + nn] = B ? B[nn] : 0.f;
    } else {
        int r = (m <= 4) ? (m - 1) : (m - 6);
        const float* W0 = (m <= 4) ? Kw : Vw;
        const float* B0 = (m <= 4) ? Kb : Vb;
        const float* Wr = (m <= 4) ? r_att : r_msg;
        int h = c, f = lane & 15;
        float wcol[16];
        #pragma unroll
        for (int jj = 0; jj < 16; jj++)
            wcol[jj] = Wr[(((size_t)r * NH + h) * DKK + jj) * DKK + f];
        #pragma unroll
        for (int j = 0; j < 8; j++) {
            const float* row = W0 + ((size_t)t * ND + (k0 + j)) * ND + h * DKK;
            float s = 0.f;
            #pragma unroll
            for (int jj = 0; jj < 16; jj++) s += row[jj] * wcol[jj];
            dst[j] = f2bf(s);
        }
        if (kb == 0 && quad == 0) {
            const float* brow = B0 + t * ND + h * DKK;
            float sb = 0.f;
            #pragma unroll
            for (int jj = 0; jj < 16; jj++) sb += brow[jj] * wcol[jj];
            bcat[(t * NMAT + m) * ND + nn] = sb;
        }
    }
}

// Tier-A FUSED: edge-count atomics || full projection (mats 0..9), with
// Bresenham-interleaved block roles so BOTH kinds are co-resident on the CUs
// (round-4's failure was edge blocks [0,ge) filling the machine first).
// Atomic waves use only the memory-side RMW units; proj waves use MFMA+stores.
__global__ void __launch_bounds__(256) k_fuse(
    int n, int e, int gproj, int gtot,
    const int* src, const int* tgt, const int* etype,
    int* cnts, int* winner, int* rank,
    const float* x_in, const int* order, const int* tcnt, const int* tstart,
    const ushort_t* Wall, const float* bcat,
    ushort_t* out_qn, ushort_t* out_kt, ushort_t* out_v1, ushort_t* out_vt)
{
    __shared__ __align__(16) ushort_t xs[4096];
    __shared__ int nodes[32];
    int bid = blockIdx.x;
    int pb  = (int)(((long long)bid * gproj) / gtot);
    int pb1 = (int)(((long long)(bid + 1) * gproj) / gtot);
    if (pb1 == pb) {
        // ---- edge-count role: eidx = count of edge blocks before bid ----
        int i = (bid - pb) * 256 + threadIdx.x;
        if (i < e) {
            rank[i] = atomicAdd(&cnts[tgt[i]], 1);
            if (etype[i] == 0) atomicMax(&winner[src[i]], i);
        }
        return;
    }
    // ---- projection role, tile index pb ----
    int b = pb;
    int nb0 = (tcnt[0] + 31) >> 5, nb1 = (tcnt[1] + 31) >> 5, nb2 = (tcnt[2] + 31) >> 5;
    int t, lb;
    if (b < nb0)                  { t = 0; lb = b; }
    else if (b < nb0 + nb1)       { t = 1; lb = b - nb0; }
    else if (b < nb0 + nb1 + nb2) { t = 2; lb = b - nb0 - nb1; }
    else return;
    int segoff = lb * 32;
    int cnt = min(32, tcnt[t] - segoff);
    int segbase = tstart[t] + segoff;
    int tid = threadIdx.x;
    if (tid < 32) nodes[tid] = (tid < cnt) ? order[segbase + tid] : -1;
    __syncthreads();
    {
        int row = tid >> 3;
        int d0 = (tid & 7) * 16;
        int rt = row >> 4, rl = row & 15;
        int kb = d0 >> 5, q0 = (d0 >> 3) & 3;
        uint4 c0, c1;
        if (row < cnt) {
            const float4* xp4 = (const float4*)(x_in + (size_t)nodes[row] * ND + d0);
            float4 a = xp4[0], b2 = xp4[1], c2 = xp4[2], d4 = xp4[3];
            c0.x = pk2(a.x, a.y);   c0.y = pk2(a.z, a.w);
            c0.z = pk2(b2.x, b2.y); c0.w = pk2(b2.z, b2.w);
            c1.x = pk2(c2.x, c2.y); c1.y = pk2(c2.z, c2.w);
            c1.z = pk2(d4.x, d4.y); c1.w = pk2(d4.z, d4.w);
        } else {
            c0.x = c0.y = c0.z = c0.w = 0u;
            c1 = c0;
        }
        *(uint4*)&xs[((rt * 4 + kb) * 64 + q0 * 16 + rl) * 8]       = c0;
        *(uint4*)&xs[((rt * 4 + kb) * 64 + (q0 + 1) * 16 + rl) * 8] = c1;
    }
    __syncthreads();

    int w = tid >> 6, lane = tid & 63;
    int rt = w & 1;
    bf16x8 afr[4];
    #pragma unroll
    for (int kb = 0; kb < 4; kb++)
        afr[kb] = as_bf16x8(*(const uint4*)&xs[((rt * 4 + kb) * 64 + lane) * 8]);
    for (int ct = (w >> 1); ct < 80; ct += 2) {   // mats 0..9
        int m = ct >> 3, c = ct & 7;
        const uint4* bp = (const uint4*)(Wall + ((((size_t)t * NMAT + m) * 8 + c) * 4) * 512);
        f32x4 acc = {0.f, 0.f, 0.f, 0.f};
        #pragma unroll
        for (int kb = 0; kb < 4; kb++) {
            bf16x8 bfr = as_bf16x8(bp[kb * 64 + lane]);
            acc = __builtin_amdgcn_mfma_f32_16x16x32_bf16(afr[kb], bfr, acc, 0, 0, 0);
        }
        int col = c * 16 + (lane & 15);
        float bias = bcat[(t * NMAT + m) * ND + col];
        int rbase = rt * 16 + (lane >> 4) * 4;
        #pragma unroll
        for (int r = 0; r < 4; r++) {
            int grow = rbase + r;
            if (grow >= cnt) continue;
            int node = nodes[grow];
            ushort_t val = f2bf(acc[r] + bias);
            if (m == 0)       out_qn[(size_t)node * ND + col] = val;
            else if (m <= 4)  out_kt[((size_t)node * NR + (m - 1)) * ND + col] = val;
            else if (m == 5)  out_v1[(size_t)node * ND + col] = val;
            else              out_vt[((size_t)node * NR + (m - 6)) * ND + col] = val;
        }
    }
}

// Tier-B projection, mats [m0, m0+nm)
__global__ void __launch_bounds__(256) k_projm(
    int n, const float* x_in, const int* order,
    const int* tcnt, const int* tstart,
    const ushort_t* Wall, const float* bcat,
    int m0, int nm,
    ushort_t* out_qn, ushort_t* out_kt, ushort_t* out_v1, ushort_t* out_vt)
{
    __shared__ __align__(16) ushort_t xs[4096];
    __shared__ int nodes[32];
    int b = blockIdx.x;
    int nb0 = (tcnt[0] + 31) >> 5, nb1 = (tcnt[1] + 31) >> 5, nb2 = (tcnt[2] + 31) >> 5;
    int t, lb;
    if (b < nb0)                  { t = 0; lb = b; }
    else if (b < nb0 + nb1)       { t = 1; lb = b - nb0; }
    else if (b < nb0 + nb1 + nb2) { t = 2; lb = b - nb0 - nb1; }
    else return;
    int segoff = lb * 32;
    int cnt = min(32, tcnt[t] - segoff);
    int segbase = tstart[t] + segoff;
    int tid = threadIdx.x;
    if (tid < 32) nodes[tid] = (tid < cnt) ? order[segbase + tid] : -1;
    __syncthreads();
    {
        int row = tid >> 3;
        int d0 = (tid & 7) * 16;
        int rt = row >> 4, rl = row & 15;
        int kb = d0 >> 5, q0 = (d0 >> 3) & 3;
        uint4 c0, c1;
        if (row < cnt) {
            const float4* xp4 = (const float4*)(x_in + (size_t)nodes[row] * ND + d0);
            float4 a = xp4[0], b2 = xp4[1], c2 = xp4[2], d4 = xp4[3];
            c0.x = pk2(a.x, a.y);   c0.y = pk2(a.z, a.w);
            c0.z = pk2(b2.x, b2.y); c0.w = pk2(b2.z, b2.w);
            c1.x = pk2(c2.x, c2.y); c1.y = pk2(c2.z, c2.w);
            c1.z = pk2(d4.x, d4.y); c1.w = pk2(d4.z, d4.w);
        } else {
            c0.x = c0.y = c0.z = c0.w = 0u;
            c1 = c0;
        }
        *(uint4*)&xs[((rt * 4 + kb) * 64 + q0 * 16 + rl) * 8]       = c0;
        *(uint4*)&xs[((rt * 4 + kb) * 64 + (q0 + 1) * 16 + rl) * 8] = c1;
    }
    __syncthreads();

    int w = tid >> 6, lane = tid & 63;
    int rt = w & 1;
    bf16x8 afr[4];
    #pragma unroll
    for (int kb = 0; kb < 4; kb++)
        afr[kb] = as_bf16x8(*(const uint4*)&xs[((rt * 4 + kb) * 64 + lane) * 8]);
    int nct = nm * 8;
    for (int ct = (w >> 1); ct < nct; ct += 2) {
        int m = m0 + (ct >> 3), c = ct & 7;
        const uint4* bp = (const uint4*)(Wall + ((((size_t)t * NMAT + m) * 8 + c) * 4) * 512);
        f32x4 acc = {0.f, 0.f, 0.f, 0.f};
        #pragma unroll
        for (int kb = 0; kb < 4; kb++) {
            bf16x8 bfr = as_bf16x8(bp[kb * 64 + lane]);
            acc = __builtin_amdgcn_mfma_f32_16x16x32_bf16(afr[kb], bfr, acc, 0, 0, 0);
        }
        int col = c * 16 + (lane & 15);
        float bias = bcat[(t * NMAT + m) * ND + col];
        int rbase = rt * 16 + (lane >> 4) * 4;
        #pragma unroll
        for (int r = 0; r < 4; r++) {
            int grow = rbase + r;
            if (grow >= cnt) continue;
            int node = nodes[grow];
            ushort_t val = f2bf(acc[r] + bias);
            if (m == 0)       out_qn[(size_t)node * ND + col] = val;
            else if (m <= 4)  out_kt[((size_t)node * NR + (m - 1)) * ND + col] = val;
            else if (m == 5)  out_v1[(size_t)node * ND + col] = val;
            else              out_vt[((size_t)node * NR + (m - 6)) * ND + col] = val;
        }
    }
}

// Tier-A: fused flash attention + aggregation, one pass over edges per node.
__global__ void __launch_bounds__(256) k_flash(
    int n, const int* off, const int* srp, const int* ntype,
    const ushort_t* qn, const ushort_t* kt, const ushort_t* vt,
    const float* r_pri, float* aggr)
{
    int wv = threadIdx.x >> 6, lane = threadIdx.x & 63;
    int i = blockIdx.x * 4 + wv;
    if (i >= n) return;
    int h = lane & 7, slot = lane >> 3;
    int hA = lane >> 3;
    int tt = ntype[i];
    float qf[16];
    load_bf8(qn + (size_t)i * ND + h * DKK, qf);
    load_bf8(qn + (size_t)i * ND + h * DKK + 8, qf + 8);
    const float* prib = r_pri + (size_t)(tt * NR * NT) * NH + h;
    int d0 = off[i], d1 = off[i + 1];
    float m = -3.0e38f, den = 0.f;
    float acc0 = 0.f, acc1 = 0.f;
    for (int p0 = d0; p0 < d1; p0 += 8) {
        int p = p0 + slot;
        bool live = (p < d1);
        int sp = live ? srp[p] : 0;
        int sr = sp & 0x0fffffff;
        int st = ((unsigned int)sp) >> 28;
        int r = sr & (NR - 1);
        float kf[16];
        const ushort_t* kp = kt + (size_t)sr * ND + h * DKK;
        load_bf8(kp, kf);
        load_bf8(kp + 8, kf + 8);
        float a = 0.f;
        #pragma unroll
        for (int f = 0; f < 16; f++) a += qf[f] * kf[f];
        float pri = prib[(r * NT + st) * NH];
        float logit = fminf(fmaxf(a * pri * 0.25f, -1.0e4f), 1.0e4f);
        if (!live) logit = -3.0e38f;
        float cm = logit;
        #pragma unroll
        for (int d = 8; d < 64; d <<= 1) cm = fmaxf(cm, __shfl_xor(cm, d, 64));
        float mnew = fmaxf(m, cm);
        float w = live ? expf(logit - mnew) : 0.f;
        float ws = w;
        #pragma unroll
        for (int d = 8; d < 64; d <<= 1) ws += __shfl_xor(ws, d, 64);
        float scale = expf(m - mnew);
        den = den * scale + ws;
        m = mnew;
        float scaleA = __shfl(scale, hA, 64);
        acc0 *= scaleA; acc1 *= scaleA;
        #pragma unroll
        for (int s = 0; s < 8; s++) {
            if (p0 + s < d1) {
                int srcl = s * 8 + hA;
                int srb  = __shfl(sr, srcl, 64);
                float wb = __shfl(w, srcl, 64);
                unsigned int u = *reinterpret_cast<const unsigned int*>(
                    vt + (size_t)srb * ND + lane * 2);
                acc0 += wb * bf2f(u & 0xffff);
                acc1 += wb * bf2f(u >> 16);
            }
        }
    }
    float denA = __shfl(den, hA, 64);
    float inv = 1.f / (denA + 1e-16f);
    float2 o; o.x = acc0 * inv; o.y = acc1 * inv;
    *reinterpret_cast<float2*>(aggr + (size_t)i * ND + lane * 2) = o;
}

// Fused speaker + GELU + A-projection + skip blend.
__global__ void __launch_bounds__(256) k_sfinal(
    int n, const float* x_in, const int* order, const int* tcnt, const int* tstart,
    const int* winner, const int* tgt, const ushort_t* v1b,
    const ushort_t* Wall, const float* bcat, const float* skip,
    const float* aggr, float* out)
{
    __shared__ __align__(16) float xf[32 * 132];
    __shared__ __align__(16) ushort_t xs[4096];
    __shared__ int nodes[32];
    __shared__ int wsrc[32];
    int b = blockIdx.x;
    int nb0 = (tcnt[0] + 31) >> 5, nb1 = (tcnt[1] + 31) >> 5, nb2 = (tcnt[2] + 31) >> 5;
    int t, lb;
    if (b < nb0)                  { t = 0; lb = b; }
    else if (b < nb0 + nb1)       { t = 1; lb = b - nb0; }
    else if (b < nb0 + nb1 + nb2) { t = 2; lb = b - nb0 - nb1; }
    else return;
    int segoff = lb * 32;
    int cnt = min(32, tcnt[t] - segoff);
    int segbase = tstart[t] + segoff;
    int tid = threadIdx.x;
    if (tid < 32) {
        int nd = (tid < cnt) ? order[segbase + tid] : -1;
        nodes[tid] = nd;
        int wi = (nd >= 0) ? winner[nd] : -1;
        wsrc[tid] = (wi >= 0) ? tgt[wi] : -1;
    }
    __syncthreads();
    // ---- stage A: pack speaker-source v1b rows into A-frag layout ----
    {
        int row = tid >> 3;
        int d0 = (tid & 7) * 16;
        int rt = row >> 4, rl = row & 15;
        int kb = d0 >> 5, q0 = (d0 >> 3) & 3;
        uint4 c0, c1;
        int s = (row < cnt) ? wsrc[row] : -1;
        if (s >= 0) {
            const uint4* vp = (const uint4*)(v1b + (size_t)s * ND + d0);
            c0 = vp[0]; c1 = vp[1];
        } else { c0.x = c0.y = c0.z = c0.w = 0u; c1 = c0; }
        *(uint4*)&xs[((rt * 4 + kb) * 64 + q0 * 16 + rl) * 8]       = c0;
        *(uint4*)&xs[((rt * 4 + kb) * 64 + (q0 + 1) * 16 + rl) * 8] = c1;
    }
    __syncthreads();
    int w = tid >> 6, lane = tid & 63;
    int rt = w & 1;
    // ---- stage B: spk = v1b-rows @ s2u ; g = gelu(aggr + spk) -> xf ----
    {
        bf16x8 afr[4];
        #pragma unroll
        for (int kb = 0; kb < 4; kb++)
            afr[kb] = as_bf16x8(*(const uint4*)&xs[((rt * 4 + kb) * 64 + lane) * 8]);
        for (int ct = (w >> 1); ct < 8; ct += 2) {
            const uint4* bp = (const uint4*)(Wall + (((size_t)11 * 8 + ct) * 4) * 512); // t=0, m=11
            f32x4 acc = {0.f, 0.f, 0.f, 0.f};
            #pragma unroll
            for (int kb = 0; kb < 4; kb++) {
                bf16x8 bfr = as_bf16x8(bp[kb * 64 + lane]);
                acc = __builtin_amdgcn_mfma_f32_16x16x32_bf16(afr[kb], bfr, acc, 0, 0, 0);
            }
            int col = ct * 16 + (lane & 15);
            int rbase = rt * 16 + (lane >> 4) * 4;
            #pragma unroll
            for (int r = 0; r < 4; r++) {
                int grow = rbase + r;
                if (grow >= cnt) continue;
                int node = nodes[grow];
                float g = aggr[(size_t)node * ND + col] + acc[r];
                g = 0.5f * g * (1.f + erff(g * 0.70710678118f));
                xf[grow * 132 + col] = g;
            }
        }
    }
    __syncthreads();
    // ---- stage C: repack gelu'd tile into A-frag layout ----
    {
        int row = tid >> 3;
        int d0 = (tid & 7) * 16;
        int rt2 = row >> 4, rl = row & 15;
        int kb = d0 >> 5, q0 = (d0 >> 3) & 3;
        uint4 c0, c1;
        if (row < cnt) {
            const float4* xp4 = (const float4*)(xf + row * 132 + d0);
            float4 a = xp4[0], b2 = xp4[1], c2 = xp4[2], d4 = xp4[3];
            c0.x = pk2(a.x, a.y);   c0.y = pk2(a.z, a.w);
            c0.z = pk2(b2.x, b2.y); c0.w = pk2(b2.z, b2.w);
            c1.x = pk2(c2.x, c2.y); c1.y = pk2(c2.z, c2.w);
            c1.z = pk2(d4.x, d4.y); c1.w = pk2(d4.z, d4.w);
        } else {
            c0.x = c0.y = c0.z = c0.w = 0u;
            c1 = c0;
        }
        *(uint4*)&xs[((rt2 * 4 + kb) * 64 + q0 * 16 + rl) * 8]       = c0;
        *(uint4*)&xs[((rt2 * 4 + kb) * 64 + (q0 + 1) * 16 + rl) * 8] = c1;
    }
    __syncthreads();
    // ---- stage D: out = (g @ Aw[t] + Ab[t]) * alpha + x_in * (1-alpha) ----
    float alpha = 1.f / (1.f + expf(-skip[t]));
    {
        bf16x8 afr[4];
        #pragma unroll
        for (int kb = 0; kb < 4; kb++)
            afr[kb] = as_bf16x8(*(const uint4*)&xs[((rt * 4 + kb) * 64 + lane) * 8]);
        for (int ct = (w >> 1); ct < 8; ct += 2) {
            const uint4* bp = (const uint4*)(Wall + ((((size_t)t * NMAT + 10) * 8 + ct) * 4) * 512);
            f32x4 acc = {0.f, 0.f, 0.f, 0.f};
            #pragma unroll
            for (int kb = 0; kb < 4; kb++) {
                bf16x8 bfr = as_bf16x8(bp[kb * 64 + lane]);
                acc = __builtin_amdgcn_mfma_f32_16x16x32_bf16(afr[kb], bfr, acc, 0, 0, 0);
            }
            int col = ct * 16 + (lane & 15);
            float bias = bcat[(t * NMAT + 10) * ND + col];
            int rbase = rt * 16 + (lane >> 4) * 4;
            #pragma unroll
            for (int r = 0; r < 4; r++) {
                int grow = rbase + r;
                if (grow >= cnt) continue;
                int node = nodes[grow];
                float xin = x_in[(size_t)node * ND + col];
                out[(size_t)node * ND + col] = (acc[r] + bias) * alpha + xin * (1.f - alpha);
            }
        }
    }
}

// Tier-B: fused logits + online segment softmax, wave per target node.
__global__ void __launch_bounds__(256) k_attmd(
    int n, const int* off, const int* srp, const int* ntype,
    const ushort_t* qn, const ushort_t* kt, const float* r_pri,
    float* atts, ushort_t* mb, float* db)
{
    int wv = threadIdx.x >> 6, lane = threadIdx.x & 63;
    int i = blockIdx.x * 4 + wv;
    if (i >= n) return;
    int h = lane & 7, slot = lane >> 3;
    int tt = ntype[i];
    float qf[16];
    load_bf8(qn + (size_t)i * ND + h * DKK, qf);
    load_bf8(qn + (size_t)i * ND + h * DKK + 8, qf + 8);
    const float* prib = r_pri + (size_t)(tt * NR * NT) * NH + h;
    int d0 = off[i], d1 = off[i + 1];
    float m = -3.0e38f, den = 0.f;
    #pragma unroll 2
    for (int p0 = d0; p0 < d1; p0 += 8) {
        int p = p0 + slot;
        bool live = (p < d1);
        int sp = live ? srp[p] : 0;
        int sr = sp & 0x0fffffff;
        int st = ((unsigned int)sp) >> 28;
        int r = sr & (NR - 1);
        float kf[16];
        const ushort_t* kp = kt + (size_t)sr * ND + h * DKK;
        load_bf8(kp, kf);
        load_bf8(kp + 8, kf + 8);
        float a = 0.f;
        #pragma unroll
        for (int f = 0; f < 16; f++) a += qf[f] * kf[f];
        float pri = prib[(r * NT + st) * NH];
        float logit = fminf(fmaxf(a * pri * 0.25f, -1.0e4f), 1.0e4f);
        if (live) {
            atts[(size_t)p * NH + h] = logit;
            float mnew = fmaxf(m, logit);
            den = den * expf(m - mnew) + expf(logit - mnew);
            m = mnew;
        }
    }
    #pragma unroll
    for (int d = 8; d < 64; d <<= 1) {
        float mo = __shfl_xor(m, d, 64);
        float dn = __shfl_xor(den, d, 64);
        float mnew = fmaxf(m, mo);
        den = den * expf(m - mnew) + dn * expf(mo - mnew);
        m = mnew;
    }
    if (slot == 0) {
        ushort_t mh = (d1 > d0) ? f2bf(m) : (ushort_t)0;
        float dfin = (d1 > d0) ? den * expf(m - bf2f(mh)) : 0.f;
        mb[i * NH + h] = mh;
        db[i * NH + h] = dfin;
    }
}

// Tier-B: wave-per-node aggregation; softmax normalize folded in
__global__ void __launch_bounds__(256) k_aggr_fast(
    int n, const int* off, const int* srp, const ushort_t* vt, const float* atts,
    const ushort_t* mb, const float* db, float* aggr)
{
    int wv = threadIdx.x >> 6, lane = threadIdx.x & 63;
    int i = blockIdx.x * 4 + wv;
    if (i >= n) return;
    int h = lane >> 3;
    float mref = bf2f(mb[i * NH + h]);
    float inv = 1.f / (db[i * NH + h] + 1e-16f);
    int d0 = off[i], d1 = off[i + 1];
    float acc0 = 0.f, acc1 = 0.f;
    #pragma unroll 4
    for (int p = d0; p < d1; p++) {
        int sr = srp[p] & 0x0fffffff;
        float w = expf(atts[(size_t)p * NH + h] - mref) * inv;
        unsigned int u = *reinterpret_cast<const unsigned int*>(
            vt + (size_t)sr * ND + lane * 2);
        acc0 += w * bf2f(u & 0xffff);
        acc1 += w * bf2f(u >> 16);
    }
    float2 o; o.x = acc0; o.y = acc1;
    *reinterpret_cast<float2*>(aggr + (size_t)i * ND + lane * 2) = o;
}

// ================= FALLBACK PATH (proven kernels) =================

__global__ void k_proj(int n, const float* x_in, const int* ntype, const int* order,
                       const float* Kw, const float* Kb,
                       const float* Qw, const float* Qb,
                       const float* Vw, const float* Vb,
                       ushort_t* kn, ushort_t* qn, ushort_t* vn, ushort_t* v1) {
    __shared__ float xs[NB][ND];
    __shared__ int nodes[NB];
    __shared__ int types[NB];
    int tid = threadIdx.x;
    int base = blockIdx.x * NB;
    int cnt = min(NB, n - base);
    if (tid < cnt) { int nd = order[base + tid]; nodes[tid] = nd; types[tid] = ntype[nd]; }
    __syncthreads();
    for (int j = 0; j < cnt; j++) xs[j][tid] = x_in[(size_t)nodes[j] * ND + tid];
    __syncthreads();
    bool uni = (types[0] == types[cnt - 1]);
    for (int m = 0; m < 4; m++) {
        const float *W, *B; ushort_t* out; int forced_t = -1;
        if (m == 0)      { W = Kw; B = Kb; out = kn; }
        else if (m == 1) { W = Qw; B = Qb; out = qn; }
        else if (m == 2) { W = Vw; B = Vb; out = vn; }
        else             { W = Vw; B = Vb; out = v1; forced_t = 1; }
        if (uni || forced_t >= 0) {
            int t = (forced_t >= 0) ? forced_t : types[0];
            float bias = B[t * ND + tid];
            float acc[NB];
            #pragma unroll
            for (int j = 0; j < NB; j++) acc[j] = bias;
            const float* Wp = W + (size_t)t * ND * ND + tid;
            for (int d = 0; d < ND; d++) {
                float w = Wp[(size_t)d * ND];
                #pragma unroll
                for (int j = 0; j < NB; j++) acc[j] += xs[j][d] * w;
            }
            for (int j = 0; j < cnt; j++) out[(size_t)nodes[j] * ND + tid] = f2bf(acc[j]);
        } else {
            for (int j = 0; j < cnt; j++) {
                int t = types[j];
                float acc = B[t * ND + tid];
                const float* Wp = W + (size_t)t * ND * ND + tid;
                for (int d = 0; d < ND; d++) acc += xs[j][d] * Wp[(size_t)d * ND];
                out[(size_t)nodes[j] * ND + tid] = f2bf(acc);
            }
        }
    }
}

__global__ void k_att(int e, const int* src, const int* tgt, const int* etype, const int* ntype,
                      const ushort_t* kn, const ushort_t* qn,
                      const float* r_att, const float* r_pri, float* att) {
    int id = blockIdx.x * 256 + threadIdx.x;
    if (id >= e * NH) return;
    int ee = id >> 3, h = id & 7;
    int s = src[ee], t = tgt[ee], r = etype[ee];
    float kf[16], qf[16];
    load_bf8(kn + (size_t)s * ND + h * DKK, kf);
    load_bf8(kn + (size_t)s * ND + h * DKK + 8, kf + 8);
    load_bf8(qn + (size_t)t * ND + h * DKK, qf);
    load_bf8(qn + (size_t)t * ND + h * DKK + 8, qf + 8);
    const float* W = r_att + (size_t)(r * NH + h) * DKK * DKK;
    float kt[16];
    #pragma unroll
    for (int f = 0; f < 16; f++) kt[f] = 0.f;
    #pragma unroll 4
    for (int d = 0; d < 16; d++) {
        float kd = kf[d];
        #pragma unroll
        for (int f = 0; f < 16; f++) kt[f] += kd * W[d * 16 + f];
    }
    float a = 0.f;
    #pragma unroll
    for (int f = 0; f < 16; f++) a += qf[f] * kt[f];
    int tt = ntype[t], st = ntype[s];
    float pri = r_pri[((tt * NR + r) * NT + st) * NH + h];
    float logit = a * pri * 0.25f;
    logit = fminf(fmaxf(logit, -1.0e4f), 1.0e4f);
    att[(size_t)ee * NH + h] = logit;
}

__global__ void k_mden(int n, const int* off, const int* sorted,
                       const float* att, ushort_t* mb, float* db) {
    int id = blockIdx.x * 256 + threadIdx.x;
    if (id >= n * NH) return;
    int i = id >> 3, h = id & 7;
    int d0 = off[i], d1 = off[i + 1];
    float m = -3.0e38f;
    for (int p = d0; p < d1; p++) m = fmaxf(m, att[(size_t)sorted[p] * NH + h]);
    ushort_t mh = (d1 > d0) ? f2bf(m) : (ushort_t)0;
    float mref = bf2f(mh);
    float den = 0.f;
    for (int p = d0; p < d1; p++) den += expf(att[(size_t)sorted[p] * NH + h] - mref);
    mb[id] = mh;
    db[id] = den;
}

__global__ void k_norm(int e, const int* tgt, const ushort_t* mb, const float* db, float* att) {
    int id = blockIdx.x * 256 + threadIdx.x;
    if (id >= e * NH) return;
    int ee = id >> 3, h = id & 7;
    int t = tgt[ee];
    float w = expf(att[id] - bf2f(mb[t * NH + h])) / (db[t * NH + h] + 1e-16f);
    att[id] = w;
}

__global__ void k_aggr(int n, const int* off, const int* sorted, const int* src, const int* etype,
                       const ushort_t* vn, const float* r_msg, const float* att, float* aggr) {
    int wv = threadIdx.x >> 6, lane = threadIdx.x & 63;
    int i = blockIdx.x * 4 + wv;
    if (i >= n) return;
    int h = lane >> 3, f0 = (lane & 7) * 2;
    int d0 = off[i], d1 = off[i + 1];
    float acc0 = 0.f, acc1 = 0.f;
    for (int p = d0; p < d1; p++) {
        int ee = sorted[p];
        int s = src[ee], r = etype[ee];
        float w = att[(size_t)ee * NH + h];
        float vj[16];
        load_bf8(vn + (size_t)s * ND + h * DKK, vj);
        load_bf8(vn + (size_t)s * ND + h * DKK + 8, vj + 8);
        const float* Wm = r_msg + (size_t)(r * NH + h) * DKK * DKK + f0;
        float a0 = 0.f, a1 = 0.f;
        #pragma unroll
        for (int d = 0; d < 16; d++) {
            a0 += vj[d] * Wm[d * 16];
            a1 += vj[d] * Wm[d * 16 + 1];
        }
        acc0 += w * a0; acc1 += w * a1;
    }
    aggr[(size_t)i * ND + h * DKK + f0]     = acc0;
    aggr[(size_t)i * ND + h * DKK + f0 + 1] = acc1;
}

__global__ void k_spk(int n, const int* winner, const int* tgt, const ushort_t* v1,
                      const float* s2u, float* aggr) {
    __shared__ float xs[NB][ND];
    __shared__ int wn[NB];
    int tid = threadIdx.x;
    int base = blockIdx.x * NB;
    int cnt = min(NB, n - base);
    if (tid < cnt) wn[tid] = winner[base + tid];
    __syncthreads();
    for (int j = 0; j < cnt; j++) {
        int w = wn[j];
        xs[j][tid] = (w >= 0) ? bf2f(v1[(size_t)tgt[w] * ND + tid]) : 0.f;
    }
    __syncthreads();
    float acc[NB];
    #pragma unroll
    for (int j = 0; j < NB; j++) acc[j] = 0.f;
    const float* Wp = s2u + tid;
    for (int d = 0; d < ND; d++) {
        float w = Wp[(size_t)d * ND];
        #pragma unroll
        for (int j = 0; j < NB; j++) acc[j] += xs[j][d] * w;
    }
    for (int j = 0; j < cnt; j++) {
        size_t idx = (size_t)(base + j) * ND + tid;
        float g = aggr[idx] + acc[j];
        g = 0.5f * g * (1.f + erff(g * 0.70710678118f));
        aggr[idx] = g;
    }
}

__global__ void k_final(int n, const float* x_in, const int* ntype, const int* order,
                        const float* Aw, const float* Ab, const float* skip,
                        const float* aggr, float* out) {
    __shared__ float xs[NB][ND];
    __shared__ int nodes[NB];
    __shared__ int types[NB];
    int tid = threadIdx.x;
    int base = blockIdx.x * NB;
    int cnt = min(NB, n - base);
    if (tid < cnt) { int nd = order[base + tid]; nodes[tid] = nd; types[tid] = ntype[nd]; }
    __syncthreads();
    for (int j = 0; j < cnt; j++) xs[j][tid] = aggr[(size_t)nodes[j] * ND + tid];
    __syncthreads();
    bool uni = (types[0] == types[cnt - 1]);
    if (uni) {
        int t = types[0];
        float bias = Ab[t * ND + tid];
        float acc[NB];
        #pragma unroll
        for (int j = 0; j < NB; j++) acc[j] = bias;
        const float* Wp = Aw + (size_t)t * ND * ND + tid;
        for (int d = 0; d < ND; d++) {
            float w = Wp[(size_t)d * ND];
            #pragma unroll
            for (int j = 0; j < NB; j++) acc[j] += xs[j][d] * w;
        }
        float alpha = 1.f / (1.f + expf(-skip[t]));
        for (int j = 0; j < cnt; j++) {
            float xin = x_in[(size_t)nodes[j] * ND + tid];
            out[(size_t)nodes[j] * ND + tid] = acc[j] * alpha + xin * (1.f - alpha);
        }
    } else {
        for (int j = 0; j < cnt; j++) {
            int t = types[j];
            float acc = Ab[t * ND + tid];
            const float* Wp = Aw + (size_t)t * ND * ND + tid;
            for (int d = 0; d < ND; d++) acc += xs[j][d] * Wp[(size_t)d * ND];
            float alpha = 1.f / (1.f + expf(-skip[t]));
            float xin = x_in[(size_t)nodes[j] * ND + tid];
            out[(size_t)nodes[j] * ND + tid] = acc * alpha + xin * (1.f - alpha);
        }
    }
}

extern "C" void kernel_launch(void* const* d_in, const int* in_sizes, int n_in,
                              void* d_out, int out_size, void* d_ws, size_t ws_size,
                              hipStream_t stream) {
    const float* node_inp = (const float*)d_in[0];
    const int* node_type  = (const int*)d_in[1];
    const int* edge_index = (const int*)d_in[2];
    const int* edge_type  = (const int*)d_in[3];
    const float* Kw = (const float*)d_in[5];
    const float* Kb = (const float*)d_in[6];
    const float* Qw = (const float*)d_in[7];
    const float* Qb = (const float*)d_in[8];
    const float* Vw = (const float*)d_in[9];
    const float* Vb = (const float*)d_in[10];
    const float* Aw = (const float*)d_in[11];
    const float* Ab = (const float*)d_in[12];
    const float* r_pri = (const float*)d_in[13];
    const float* r_att = (const float*)d_in[14];
    const float* r_msg = (const float*)d_in[15];
    const float* s2u   = (const float*)d_in[16];
    const float* skip  = (const float*)d_in[17];

    int n = in_sizes[1];
    int e = in_sizes[3];
    const int* srcp = edge_index;
    const int* tgtp = edge_index + e;

    char* wsp = (char*)d_ws;
    size_t woff = 0;
    auto alloc = [&](size_t b) { void* p = wsp + woff; woff += (b + 255) & ~(size_t)255; return p; };

    // ---- common infra ----
    int* offs     = (int*)alloc((size_t)(n + 1) * 4);   // counts, then in-place prefix
    int* winner   = (int*)alloc((size_t)n * 4);
    int* order    = (int*)alloc((size_t)n * 4);
    int* tcnt     = (int*)alloc(16);
    int* tstart   = (int*)alloc(16);
    int* nb4      = (int*)alloc(4096);
    int* nboff4   = (int*)alloc(4096);
    int* ob       = (int*)alloc(4096);
    int* oboff    = (int*)alloc(4096);
    int* eord     = (int*)alloc((size_t)e * 4);   // fast: srp record; fallback: sorted edge id
    ushort_t* mb  = (ushort_t*)alloc((size_t)n * NH * 2);
    float* db     = (float*)alloc((size_t)n * NH * 4);
    ushort_t* v1b = (ushort_t*)alloc((size_t)n * ND * 2);
    float* att    = (float*)alloc((size_t)e * NH * 4);
    size_t commonEnd = woff;

    // rank lives in att's space: written by count, dead after scatter.
    int* rank = (int*)att;

    // ---- Tier B layout ----
    woff = commonEnd;
    ushort_t* WallB = (ushort_t*)alloc((size_t)NT * NMAT * 8 * 4 * 512 * 2);
    float* bcatB    = (float*)alloc((size_t)NT * NMAT * ND * 4);
    char* F         = (char*)alloc((size_t)n * 1536);   // phase1: qn+kt; phase2: vt+aggr
    size_t fastEnd = woff;

    // ---- Tier A (flash) layout: qn+kt+vt live together; aggr overlays att ----
    woff = commonEnd;
    ushort_t* WallA = (ushort_t*)alloc((size_t)NT * NMAT * 8 * 4 * 512 * 2);
    float* bcatA    = (float*)alloc((size_t)NT * NMAT * ND * 4);
    ushort_t* qnA   = (ushort_t*)alloc((size_t)n * ND * 2);
    ushort_t* ktA   = (ushort_t*)alloc((size_t)n * NR * ND * 2);
    ushort_t* vtA   = (ushort_t*)alloc((size_t)n * NR * ND * 2);
    size_t tierAEnd = woff;
    float* aggrA = (float*)att;   // requires e*NH*4 >= n*ND*4 (equal here); rank dead by then

    int gn = (n + 255) / 256;
    int ge = (e + 255) / 256;
    int nbscan = n / SCB + 1;
    int gproj = (n + 31) / 32 + NT;

    int tierA = (ws_size >= tierAEnd) && ((size_t)e * NH >= (size_t)n * ND);
    int fast  = (ws_size >= fastEnd);

    // edge-independent prelude: zero counters + stable node partition
    k_zero<<<gn, 256, 0, stream>>>(n, offs, winner);
    k_nscanA<<<nbscan, 256, 0, stream>>>(n, node_type, nb4);
    k_nscanB<<<1, 64, 0, stream>>>(nbscan, nb4, nboff4, tcnt, tstart);
    k_nscanC<<<nbscan, 256, 0, stream>>>(n, node_type, nboff4, tstart, order);

    if (tierA) {
        // ======== TIER A: count || projection fused, then flash + epilogue ========
        k_pack<<<NT * NMAT * 8 * 4, 64, 0, stream>>>(Qw, Qb, Kw, Kb, Vw, Vb, Aw, Ab,
                                                     s2u, r_att, r_msg, WallA, bcatA);
        int gtot = gproj + ge;
        k_fuse<<<gtot, 256, 0, stream>>>(n, e, gproj, gtot, srcp, tgtp, edge_type,
                                         offs, winner, rank,
                                         node_inp, order, tcnt, tstart, WallA, bcatA,
                                         qnA, ktA, v1b, vtA);
        k_oscanA<<<nbscan, 256, 0, stream>>>(n, offs, ob);
        k_oscanB<<<1, 64, 0, stream>>>(nbscan, ob, oboff);
        k_oscanC<<<nbscan, 256, 0, stream>>>(n, offs, oboff);
        k_scatter<<<ge, 256, 0, stream>>>(e, srcp, tgtp, edge_type, node_type,
                                          offs, rank, eord, 1);
        k_flash<<<(n + 3) / 4, 256, 0, stream>>>(n, offs, eord, node_type,
                                                 qnA, ktA, vtA, r_pri, aggrA);
        k_sfinal<<<gproj, 256, 0, stream>>>(n, node_inp, order, tcnt, tstart,
                                            winner, tgtp, v1b, WallA, bcatA, skip,
                                            aggrA, (float*)d_out);
    } else if (fast) {
        // ======== TIER B ========
        ushort_t* qn  = (ushort_t*)F;
        ushort_t* kt  = (ushort_t*)(F + (size_t)n * 256);
        ushort_t* vt  = (ushort_t*)F;                         // overlays qn+kt (dead after k_attmd)
        float* aggr   = (float*)(F + (size_t)n * 1024);       // overlays kt tail (dead)

        k_count<<<ge, 256, 0, stream>>>(e, srcp, tgtp, edge_type, offs, winner, rank);
        k_oscanA<<<nbscan, 256, 0, stream>>>(n, offs, ob);
        k_oscanB<<<1, 64, 0, stream>>>(nbscan, ob, oboff);
        k_oscanC<<<nbscan, 256, 0, stream>>>(n, offs, oboff);
        k_scatter<<<ge, 256, 0, stream>>>(e, srcp, tgtp, edge_type, node_type,
                                          offs, rank, eord, 1);
        k_pack<<<NT * NMAT * 8 * 4, 64, 0, stream>>>(Qw, Qb, Kw, Kb, Vw, Vb, Aw, Ab,
                                                     s2u, r_att, r_msg, WallB, bcatB);
        k_projm<<<gproj, 256, 0, stream>>>(n, node_inp, order, tcnt, tstart, WallB, bcatB,
                                           0, 6, qn, kt, v1b, (ushort_t*)nullptr);
        k_attmd<<<(n + 3) / 4, 256, 0, stream>>>(n, offs, eord, node_type,
                                                 qn, kt, r_pri, att, mb, db);
        k_projm<<<gproj, 256, 0, stream>>>(n, node_inp, order, tcnt, tstart, WallB, bcatB,
                                           6, 4, (ushort_t*)nullptr, (ushort_t*)nullptr,
                                           (ushort_t*)nullptr, vt);
        k_aggr_fast<<<(n + 3) / 4, 256, 0, stream>>>(n, offs, eord, vt, att, mb, db, aggr);
        k_sfinal<<<gproj, 256, 0, stream>>>(n, node_inp, order, tcnt, tstart,
                                            winner, tgtp, v1b, WallB, bcatB, skip,
                                            aggr, (float*)d_out);
    } else {
        // ======== FALLBACK ========
        woff = commonEnd;
        ushort_t* vn  = (ushort_t*)alloc((size_t)n * ND * 2);
        char* regA    = (char*)alloc((size_t)n * ND * 2 * 2);
        ushort_t* kn  = (ushort_t*)regA;
        ushort_t* qn  = (ushort_t*)(regA + (size_t)n * ND * 2);
        float* aggr   = (float*)regA;

        k_count<<<ge, 256, 0, stream>>>(e, srcp, tgtp, edge_type, offs, winner, rank);
        k_oscanA<<<nbscan, 256, 0, stream>>>(n, offs, ob);
        k_oscanB<<<1, 64, 0, stream>>>(nbscan, ob, oboff);
        k_oscanC<<<nbscan, 256, 0, stream>>>(n, offs, oboff);
        k_scatter<<<ge, 256, 0, stream>>>(e, srcp, tgtp, edge_type, node_type,
                                          offs, rank, eord, 0);
        k_proj<<<(n + NB - 1) / NB, 128, 0, stream>>>(n, node_inp, node_type, order,
                                                      Kw, Kb, Qw, Qb, Vw, Vb, kn, qn, vn, v1b);
        k_att<<<(e * NH + 255) / 256, 256, 0, stream>>>(e, srcp, tgtp, edge_type, node_type,
                                                        kn, qn, r_att, r_pri, att);
        k_mden<<<(n * NH + 255) / 256, 256, 0, stream>>>(n, offs, eord, att, mb, db);
        k_norm<<<(e * NH + 255) / 256, 256, 0, stream>>>(e, tgtp, mb, db, att);
        k_aggr<<<(n + 3) / 4, 256, 0, stream>>>(n, offs, eord, srcp, edge_type, vn, r_msg, att, aggr);
        k_spk<<<(n + NB - 1) / NB, 128, 0, stream>>>(n, winner, tgtp, v1b, s2u, aggr);
        k_final<<<(n + NB - 1) / NB, 128, 0, stream>>>(n, node_inp, node_type, order,
                                                       Aw, Ab, skip, aggr, (float*)d_out);
    }
}

// Round 10
// 313.261 us; speedup vs baseline: 1.0533x; 1.0533x over previous
//
#include <hip/hip_runtime.h>
#include <hip/hip_bf16.h>
#include <math.h>

#define ND 128
#define NH 8
#define DKK 16
#define NT 3
#define NR 4
#define NB 8
#define NMAT 12   // pack: 0=Q, 1..4=K@att[r], 5=V(type1), 6..9=V@msg[r], 10=A, 11=s2u
#define SCB 4096  // scan elems per block (256 threads x 16)

typedef unsigned short ushort_t;
typedef __bf16 bf16_t;
typedef bf16_t bf16x8 __attribute__((ext_vector_type(8)));
typedef float f32x4 __attribute__((ext_vector_type(4)));

__device__ __forceinline__ float bf2f(unsigned short u) {
    union { unsigned int i; float f; } v; v.i = ((unsigned int)u) << 16; return v.f;
}
__device__ __forceinline__ unsigned short f2bf(float f) {
    union { float f; unsigned int i; } v; v.f = f;
    unsigned int x = v.i;
    unsigned int lsb = (x >> 16) & 1u;
    x += 0x7fffu + lsb;
    return (unsigned short)(x >> 16);
}
__device__ __forceinline__ unsigned int pk2(float a, float b) {
    return (unsigned int)f2bf(a) | ((unsigned int)f2bf(b) << 16);
}
__device__ __forceinline__ void load_bf8(const ushort_t* p, float* o) {
    uint4 u = *reinterpret_cast<const uint4*>(p);
    o[0]=bf2f(u.x & 0xffff); o[1]=bf2f(u.x >> 16);
    o[2]=bf2f(u.y & 0xffff); o[3]=bf2f(u.y >> 16);
    o[4]=bf2f(u.z & 0xffff); o[5]=bf2f(u.z >> 16);
    o[6]=bf2f(u.w & 0xffff); o[7]=bf2f(u.w >> 16);
}
__device__ __forceinline__ void cvt8(uint4 u, float* o) {
    o[0]=bf2f(u.x & 0xffff); o[1]=bf2f(u.x >> 16);
    o[2]=bf2f(u.y & 0xffff); o[3]=bf2f(u.y >> 16);
    o[4]=bf2f(u.z & 0xffff); o[5]=bf2f(u.z >> 16);
    o[6]=bf2f(u.w & 0xffff); o[7]=bf2f(u.w >> 16);
}
__device__ __forceinline__ bf16x8 as_bf16x8(uint4 u) {
    union { uint4 u; bf16x8 v; } c; c.u = u; return c.v;
}

// ---------------- sort / bucket infrastructure ----------------

__global__ void k_zero(int n, int* offs, int* winner) {
    int i = blockIdx.x * 256 + threadIdx.x;
    if (i < n) { offs[i] = 0; winner[i] = -1; }
}

// Edge counting: the atomicAdd RETURN VALUE is the edge's rank within its
// target bucket -> k_scatter needs no atomics.
__global__ void k_count(int e, const int* src, const int* tgt, const int* etype,
                        int* offs, int* winner, int* rank) {
    int i = blockIdx.x * 256 + threadIdx.x;
    if (i < e) {
        rank[i] = atomicAdd(&offs[tgt[i]], 1);
        if (etype[i] == 0) atomicMax(&winner[src[i]], i);  // last-write-wins == max edge id
    }
}

// ---- multi-block scan: offs prefix AND stable 3-way type partition ----
// bsum4/boff4: per block [offs_sum, cnt_t0, cnt_t1, cnt_t2]

__global__ void k_scanA(int n, const int* offs, const int* ntype, int* bsum4) {
    __shared__ int red[256];
    __shared__ int tr[256][3];
    int b = blockIdx.x, tid = threadIdx.x;
    int base = b * SCB + tid * 16;
    int s = 0, c0 = 0, c1 = 0, c2 = 0;
    #pragma unroll
    for (int i = 0; i < 16; i++) {
        int idx = base + i;
        if (idx < n) {
            s += offs[idx];
            int t = ntype[idx];
            c0 += (t == 0); c1 += (t == 1); c2 += (t == 2);
        }
    }
    red[tid] = s; tr[tid][0] = c0; tr[tid][1] = c1; tr[tid][2] = c2;
    __syncthreads();
    for (int d = 128; d > 0; d >>= 1) {
        if (tid < d) {
            red[tid] += red[tid + d];
            tr[tid][0] += tr[tid + d][0];
            tr[tid][1] += tr[tid + d][1];
            tr[tid][2] += tr[tid + d][2];
        }
        __syncthreads();
    }
    if (tid == 0) {
        bsum4[b * 4]     = red[0];
        bsum4[b * 4 + 1] = tr[0][0];
        bsum4[b * 4 + 2] = tr[0][1];
        bsum4[b * 4 + 3] = tr[0][2];
    }
}

__global__ void k_scanB(int nb, const int* bsum4, int* boff4, int* tcnt, int* tstart) {
    if (threadIdx.x == 0) {
        int run = 0, r0 = 0, r1 = 0, r2 = 0;
        for (int b = 0; b < nb; b++) {
            boff4[b * 4]     = run;
            boff4[b * 4 + 1] = r0;
            boff4[b * 4 + 2] = r1;
            boff4[b * 4 + 3] = r2;
            run += bsum4[b * 4];
            r0  += bsum4[b * 4 + 1];
            r1  += bsum4[b * 4 + 2];
            r2  += bsum4[b * 4 + 3];
        }
        tcnt[0] = r0; tcnt[1] = r1; tcnt[2] = r2;
        tstart[0] = 0; tstart[1] = r0; tstart[2] = r0 + r1;
    }
}

// offs -> exclusive prefix; order -> STABLE type partition (ascending node id
// within each type segment): sequential-row access for all tile kernels.
__global__ void k_scanC(int n, int* offs, const int* ntype, const int* boff4,
                        const int* tstart, int* order) {
    __shared__ int red[256];
    __shared__ int tr[256][3];
    int b = blockIdx.x, tid = threadIdx.x;
    int base = b * SCB + tid * 16;
    int v[16]; signed char ty[16];
    int s = 0, c0 = 0, c1 = 0, c2 = 0;
    #pragma unroll
    for (int i = 0; i < 16; i++) {
        int idx = base + i;
        v[i] = (idx < n) ? offs[idx] : 0;
        s += v[i];
        int t = (idx < n) ? ntype[idx] : -1;
        ty[i] = (signed char)t;
        c0 += (t == 0); c1 += (t == 1); c2 += (t == 2);
    }
    red[tid] = s; tr[tid][0] = c0; tr[tid][1] = c1; tr[tid][2] = c2;
    __syncthreads();
    for (int d = 1; d < 256; d <<= 1) {
        int vv = (tid >= d) ? red[tid - d] : 0;
        int w0 = (tid >= d) ? tr[tid - d][0] : 0;
        int w1 = (tid >= d) ? tr[tid - d][1] : 0;
        int w2 = (tid >= d) ? tr[tid - d][2] : 0;
        __syncthreads();
        red[tid] += vv; tr[tid][0] += w0; tr[tid][1] += w1; tr[tid][2] += w2;
        __syncthreads();
    }
    int run = boff4[b * 4] + red[tid] - s;          // exclusive offs prefix
    int p0 = tstart[0] + boff4[b * 4 + 1] + tr[tid][0] - c0;
    int p1 = tstart[1] + boff4[b * 4 + 2] + tr[tid][1] - c1;
    int p2 = tstart[2] + boff4[b * 4 + 3] + tr[tid][2] - c2;
    #pragma unroll
    for (int i = 0; i < 16; i++) {
        int idx = base + i;
        if (idx < n) {
            offs[idx] = run; run += v[i];
            int t = ty[i];
            if (t == 0)      order[p0++] = idx;
            else if (t == 1) order[p1++] = idx;
            else             order[p2++] = idx;
        }
    }
    if (base <= n && n < base + 16) offs[n] = run;   // grand total
}

// ATOMIC-FREE edge scatter: slot = scanned offs + precomputed rank.
// mode=1: eord[p] = (src*NR+etype) | ntype[src]<<28 ; mode=0: eord[p] = edge id
__global__ void k_scatter(int e, const int* src, const int* tgt, const int* etype,
                          const int* ntype, const int* offs, const int* rank,
                          int* eord, int mode) {
    int i = blockIdx.x * 256 + threadIdx.x;
    if (i < e) {
        int p = offs[tgt[i]] + rank[i];
        if (mode) {
            int s = src[i];
            eord[p] = (s * NR + etype[i]) | (ntype[s] << 28);
        } else {
            eord[p] = i;
        }
    }
}

// ================= PACK (12 mats, proven) =================

__global__ void k_pack(const float* Qw, const float* Qb, const float* Kw, const float* Kb,
                       const float* Vw, const float* Vb, const float* Aw, const float* Ab,
                       const float* s2u, const float* r_att, const float* r_msg,
                       ushort_t* Wall, float* bcat) {
    int blk = blockIdx.x;
    int kb = blk & 3;
    int c = (blk >> 2) & 7;
    int tm = blk >> 5;
    int m = tm % NMAT, t = tm / NMAT;
    int lane = threadIdx.x;
    int nn = c * 16 + (lane & 15);
    int quad = lane >> 4;
    int k0 = kb * 32 + quad * 8;
    ushort_t* dst = Wall + (size_t)blk * 512 + lane * 8;

    if (m == 0 || m == 5 || m == 10 || m == 11) {
        const float* W; const float* B;
        if (m == 0)       { W = Qw + (size_t)t * ND * ND; B = Qb + t * ND; }
        else if (m == 5)  { W = Vw + (size_t)ND * ND;     B = Vb + ND; }
        else if (m == 10) { W = Aw + (size_t)t * ND * ND; B = Ab + t * ND; }
        else              { W = s2u;                      B = nullptr; }
        #pragma unroll
        for (int j = 0; j < 8; j++) dst[j] = f2bf(W[(size_t)(k0 + j) * ND + nn]);
        if (kb == 0 && quad == 0)
            bcat[(t * NMAT + m) * ND + nn] = B ? B[nn] : 0.f;
    } else {
        int r = (m <= 4) ? (m - 1) : (m - 6);
        const float* W0 = (m <= 4) ? Kw : Vw;
        const float* B0 = (m <= 4) ? Kb : Vb;
        const float* Wr = (m <= 4) ? r_att : r_msg;
        int h = c, f = lane & 15;
        float wcol[16];
        #pragma unroll
        for (int jj = 0; jj < 16; jj++)
            wcol[jj] = Wr[(((size_t)r * NH + h) * DKK + jj) * DKK + f];
        #pragma unroll
        for (int j = 0; j < 8; j++) {
            const float* row = W0 + ((size_t)t * ND + (k0 + j)) * ND + h * DKK;
            float s = 0.f;
            #pragma unroll
            for (int jj = 0; jj < 16; jj++) s += row[jj] * wcol[jj];
            dst[j] = f2bf(s);
        }
        if (kb == 0 && quad == 0) {
            const float* brow = B0 + t * ND + h * DKK;
            float sb = 0.f;
            #pragma unroll
            for (int jj = 0; jj < 16; jj++) sb += brow[jj] * wcol[jj];
            bcat[(t * NMAT + m) * ND + nn] = sb;
        }
    }
}

// Tier-B projection, mats [m0, m0+nm)
__global__ void __launch_bounds__(256) k_projm(
    int n, const float* x_in, const int* order,
    const int* tcnt, const int* tstart,
    const ushort_t* Wall, const float* bcat,
    int m0, int nm,
    ushort_t* out_qn, ushort_t* out_kt, ushort_t* out_v1, ushort_t* out_vt)
{
    __shared__ __align__(16) ushort_t xs[4096];
    __shared__ int nodes[32];
    int b = blockIdx.x;
    int nb0 = (tcnt[0] + 31) >> 5, nb1 = (tcnt[1] + 31) >> 5, nb2 = (tcnt[2] + 31) >> 5;
    int t, lb;
    if (b < nb0)                  { t = 0; lb = b; }
    else if (b < nb0 + nb1)       { t = 1; lb = b - nb0; }
    else if (b < nb0 + nb1 + nb2) { t = 2; lb = b - nb0 - nb1; }
    else return;
    int segoff = lb * 32;
    int cnt = min(32, tcnt[t] - segoff);
    int segbase = tstart[t] + segoff;
    int tid = threadIdx.x;
    if (tid < 32) nodes[tid] = (tid < cnt) ? order[segbase + tid] : -1;
    __syncthreads();
    {
        int row = tid >> 3;
        int d0 = (tid & 7) * 16;
        int rt = row >> 4, rl = row & 15;
        int kb = d0 >> 5, q0 = (d0 >> 3) & 3;
        uint4 c0, c1;
        if (row < cnt) {
            const float4* xp4 = (const float4*)(x_in + (size_t)nodes[row] * ND + d0);
            float4 a = xp4[0], b2 = xp4[1], c2 = xp4[2], d4 = xp4[3];
            c0.x = pk2(a.x, a.y);   c0.y = pk2(a.z, a.w);
            c0.z = pk2(b2.x, b2.y); c0.w = pk2(b2.z, b2.w);
            c1.x = pk2(c2.x, c2.y); c1.y = pk2(c2.z, c2.w);
            c1.z = pk2(d4.x, d4.y); c1.w = pk2(d4.z, d4.w);
        } else {
            c0.x = c0.y = c0.z = c0.w = 0u;
            c1 = c0;
        }
        *(uint4*)&xs[((rt * 4 + kb) * 64 + q0 * 16 + rl) * 8]       = c0;
        *(uint4*)&xs[((rt * 4 + kb) * 64 + (q0 + 1) * 16 + rl) * 8] = c1;
    }
    __syncthreads();

    int w = tid >> 6, lane = tid & 63;
    int rt = w & 1;
    bf16x8 afr[4];
    #pragma unroll
    for (int kb = 0; kb < 4; kb++)
        afr[kb] = as_bf16x8(*(const uint4*)&xs[((rt * 4 + kb) * 64 + lane) * 8]);
    int nct = nm * 8;
    for (int ct = (w >> 1); ct < nct; ct += 2) {
        int m = m0 + (ct >> 3), c = ct & 7;
        const uint4* bp = (const uint4*)(Wall + ((((size_t)t * NMAT + m) * 8 + c) * 4) * 512);
        f32x4 acc = {0.f, 0.f, 0.f, 0.f};
        #pragma unroll
        for (int kb = 0; kb < 4; kb++) {
            bf16x8 bfr = as_bf16x8(bp[kb * 64 + lane]);
            acc = __builtin_amdgcn_mfma_f32_16x16x32_bf16(afr[kb], bfr, acc, 0, 0, 0);
        }
        int col = c * 16 + (lane & 15);
        float bias = bcat[(t * NMAT + m) * ND + col];
        int rbase = rt * 16 + (lane >> 4) * 4;
        #pragma unroll
        for (int r = 0; r < 4; r++) {
            int grow = rbase + r;
            if (grow >= cnt) continue;
            int node = nodes[grow];
            ushort_t val = f2bf(acc[r] + bias);
            if (m == 0)       out_qn[(size_t)node * ND + col] = val;
            else if (m <= 4)  out_kt[((size_t)node * NR + (m - 1)) * ND + col] = val;
            else if (m == 5)  out_v1[(size_t)node * ND + col] = val;
            else              out_vt[((size_t)node * NR + (m - 6)) * ND + col] = val;
        }
    }
}

// Tier-A projection: all mats 0..9 in ONE launch (x staged once).
__global__ void __launch_bounds__(256) k_projall(
    int n, const float* x_in, const int* order,
    const int* tcnt, const int* tstart,
    const ushort_t* Wall, const float* bcat,
    ushort_t* out_qn, ushort_t* out_kt, ushort_t* out_v1, ushort_t* out_vt)
{
    __shared__ __align__(16) ushort_t xs[4096];
    __shared__ int nodes[32];
    int b = blockIdx.x;
    int nb0 = (tcnt[0] + 31) >> 5, nb1 = (tcnt[1] + 31) >> 5, nb2 = (tcnt[2] + 31) >> 5;
    int t, lb;
    if (b < nb0)                  { t = 0; lb = b; }
    else if (b < nb0 + nb1)       { t = 1; lb = b - nb0; }
    else if (b < nb0 + nb1 + nb2) { t = 2; lb = b - nb0 - nb1; }
    else return;
    int segoff = lb * 32;
    int cnt = min(32, tcnt[t] - segoff);
    int segbase = tstart[t] + segoff;
    int tid = threadIdx.x;
    if (tid < 32) nodes[tid] = (tid < cnt) ? order[segbase + tid] : -1;
    __syncthreads();
    {
        int row = tid >> 3;
        int d0 = (tid & 7) * 16;
        int rt = row >> 4, rl = row & 15;
        int kb = d0 >> 5, q0 = (d0 >> 3) & 3;
        uint4 c0, c1;
        if (row < cnt) {
            const float4* xp4 = (const float4*)(x_in + (size_t)nodes[row] * ND + d0);
            float4 a = xp4[0], b2 = xp4[1], c2 = xp4[2], d4 = xp4[3];
            c0.x = pk2(a.x, a.y);   c0.y = pk2(a.z, a.w);
            c0.z = pk2(b2.x, b2.y); c0.w = pk2(b2.z, b2.w);
            c1.x = pk2(c2.x, c2.y); c1.y = pk2(c2.z, c2.w);
            c1.z = pk2(d4.x, d4.y); c1.w = pk2(d4.z, d4.w);
        } else {
            c0.x = c0.y = c0.z = c0.w = 0u;
            c1 = c0;
        }
        *(uint4*)&xs[((rt * 4 + kb) * 64 + q0 * 16 + rl) * 8]       = c0;
        *(uint4*)&xs[((rt * 4 + kb) * 64 + (q0 + 1) * 16 + rl) * 8] = c1;
    }
    __syncthreads();

    int w = tid >> 6, lane = tid & 63;
    int rt = w & 1;
    bf16x8 afr[4];
    #pragma unroll
    for (int kb = 0; kb < 4; kb++)
        afr[kb] = as_bf16x8(*(const uint4*)&xs[((rt * 4 + kb) * 64 + lane) * 8]);
    for (int ct = (w >> 1); ct < 80; ct += 2) {   // mats 0..9
        int m = ct >> 3, c = ct & 7;
        const uint4* bp = (const uint4*)(Wall + ((((size_t)t * NMAT + m) * 8 + c) * 4) * 512);
        f32x4 acc = {0.f, 0.f, 0.f, 0.f};
        #pragma unroll
        for (int kb = 0; kb < 4; kb++) {
            bf16x8 bfr = as_bf16x8(bp[kb * 64 + lane]);
            acc = __builtin_amdgcn_mfma_f32_16x16x32_bf16(afr[kb], bfr, acc, 0, 0, 0);
        }
        int col = c * 16 + (lane & 15);
        float bias = bcat[(t * NMAT + m) * ND + col];
        int rbase = rt * 16 + (lane >> 4) * 4;
        #pragma unroll
        for (int r = 0; r < 4; r++) {
            int grow = rbase + r;
            if (grow >= cnt) continue;
            int node = nodes[grow];
            ushort_t val = f2bf(acc[r] + bias);
            if (m == 0)       out_qn[(size_t)node * ND + col] = val;
            else if (m <= 4)  out_kt[((size_t)node * NR + (m - 1)) * ND + col] = val;
            else if (m == 5)  out_v1[(size_t)node * ND + col] = val;
            else              out_vt[((size_t)node * NR + (m - 6)) * ND + col] = val;
        }
    }
}

// Tier-A: fused flash attention + aggregation, one pass over edges per node.
// 2-deep software pipeline: stage next chunk's srp + raw K row during current
// chunk's compute; issue current chunk's V words before the shfl reductions.
__global__ void __launch_bounds__(256) k_flash(
    int n, const int* off, const int* srp, const int* ntype,
    const ushort_t* qn, const ushort_t* kt, const ushort_t* vt,
    const float* r_pri, float* aggr)
{
    int wv = threadIdx.x >> 6, lane = threadIdx.x & 63;
    int i = blockIdx.x * 4 + wv;
    if (i >= n) return;
    int h = lane & 7, slot = lane >> 3;
    int hA = lane >> 3;
    int tt = ntype[i];
    float qf[16];
    load_bf8(qn + (size_t)i * ND + h * DKK, qf);
    load_bf8(qn + (size_t)i * ND + h * DKK + 8, qf + 8);
    const float* prib = r_pri + (size_t)(tt * NR * NT) * NH + h;
    int d0 = off[i], d1 = off[i + 1];
    float m = -3.0e38f, den = 0.f;
    float acc0 = 0.f, acc1 = 0.f;
    // ---- pipeline prologue: stage chunk 0 ----
    int sp_c = 0; bool live_c = false;
    uint4 ka_c, kb_c;
    ka_c.x = ka_c.y = ka_c.z = ka_c.w = 0u; kb_c = ka_c;
    if (d0 < d1) {
        int p = d0 + slot;
        live_c = (p < d1);
        sp_c = live_c ? srp[p] : 0;
        const uint4* kp = (const uint4*)(kt + (size_t)(sp_c & 0x0fffffff) * ND + h * DKK);
        ka_c = kp[0]; kb_c = kp[1];
    }
    for (int p0 = d0; p0 < d1; p0 += 8) {
        // ---- stage next chunk (loads in flight across this iteration) ----
        int np0 = p0 + 8;
        int sp_n = 0; bool live_n = false;
        uint4 ka_n, kb_n;
        ka_n.x = ka_n.y = ka_n.z = ka_n.w = 0u; kb_n = ka_n;
        if (np0 < d1) {
            int p = np0 + slot;
            live_n = (p < d1);
            sp_n = live_n ? srp[p] : 0;
            const uint4* kp = (const uint4*)(kt + (size_t)(sp_n & 0x0fffffff) * ND + h * DKK);
            ka_n = kp[0]; kb_n = kp[1];
        }
        // ---- compute current chunk ----
        int sr = sp_c & 0x0fffffff;
        int st = ((unsigned int)sp_c) >> 28;
        int r = sr & (NR - 1);
        float kf[16];
        cvt8(ka_c, kf); cvt8(kb_c, kf + 8);
        float a = 0.f;
        #pragma unroll
        for (int f = 0; f < 16; f++) a += qf[f] * kf[f];
        float pri = prib[(r * NT + st) * NH];
        float logit = fminf(fmaxf(a * pri * 0.25f, -1.0e4f), 1.0e4f);
        if (!live_c) logit = -3.0e38f;
        // early V issue: addresses depend only on sr, not on the weights
        int nlive = min(d1 - p0, 8);
        unsigned int u[8];
        #pragma unroll
        for (int s = 0; s < 8; s++) {
            int srb = __shfl(sr, s * 8 + hA, 64);
            u[s] = (s < nlive) ? *reinterpret_cast<const unsigned int*>(
                        vt + (size_t)srb * ND + lane * 2) : 0u;
        }
        float cm = logit;
        #pragma unroll
        for (int d = 8; d < 64; d <<= 1) cm = fmaxf(cm, __shfl_xor(cm, d, 64));
        float mnew = fmaxf(m, cm);
        float w = live_c ? expf(logit - mnew) : 0.f;
        float ws = w;
        #pragma unroll
        for (int d = 8; d < 64; d <<= 1) ws += __shfl_xor(ws, d, 64);
        float scale = expf(m - mnew);
        den = den * scale + ws;
        m = mnew;
        float scaleA = __shfl(scale, hA, 64);
        acc0 *= scaleA; acc1 *= scaleA;
        #pragma unroll
        for (int s = 0; s < 8; s++) {
            if (s < nlive) {
                float wb = __shfl(w, s * 8 + hA, 64);
                acc0 += wb * bf2f(u[s] & 0xffff);
                acc1 += wb * bf2f(u[s] >> 16);
            }
        }
        // ---- rotate pipeline ----
        sp_c = sp_n; live_c = live_n; ka_c = ka_n; kb_c = kb_n;
    }
    float denA = __shfl(den, hA, 64);
    float inv = 1.f / (denA + 1e-16f);
    float2 o; o.x = acc0 * inv; o.y = acc1 * inv;
    *reinterpret_cast<float2*>(aggr + (size_t)i * ND + lane * 2) = o;
}

// Fused speaker + GELU + A-projection + skip blend.
__global__ void __launch_bounds__(256) k_sfinal(
    int n, const float* x_in, const int* order, const int* tcnt, const int* tstart,
    const int* winner, const int* tgt, const ushort_t* v1b,
    const ushort_t* Wall, const float* bcat, const float* skip,
    const float* aggr, float* out)
{
    __shared__ __align__(16) float xf[32 * 132];
    __shared__ __align__(16) ushort_t xs[4096];
    __shared__ int nodes[32];
    __shared__ int wsrc[32];
    int b = blockIdx.x;
    int nb0 = (tcnt[0] + 31) >> 5, nb1 = (tcnt[1] + 31) >> 5, nb2 = (tcnt[2] + 31) >> 5;
    int t, lb;
    if (b < nb0)                  { t = 0; lb = b; }
    else if (b < nb0 + nb1)       { t = 1; lb = b - nb0; }
    else if (b < nb0 + nb1 + nb2) { t = 2; lb = b - nb0 - nb1; }
    else return;
    int segoff = lb * 32;
    int cnt = min(32, tcnt[t] - segoff);
    int segbase = tstart[t] + segoff;
    int tid = threadIdx.x;
    if (tid < 32) {
        int nd = (tid < cnt) ? order[segbase + tid] : -1;
        nodes[tid] = nd;
        int wi = (nd >= 0) ? winner[nd] : -1;
        wsrc[tid] = (wi >= 0) ? tgt[wi] : -1;
    }
    __syncthreads();
    // ---- stage A: pack speaker-source v1b rows into A-frag layout ----
    {
        int row = tid >> 3;
        int d0 = (tid & 7) * 16;
        int rt = row >> 4, rl = row & 15;
        int kb = d0 >> 5, q0 = (d0 >> 3) & 3;
        uint4 c0, c1;
        int s = (row < cnt) ? wsrc[row] : -1;
        if (s >= 0) {
            const uint4* vp = (const uint4*)(v1b + (size_t)s * ND + d0);
            c0 = vp[0]; c1 = vp[1];
        } else { c0.x = c0.y = c0.z = c0.w = 0u; c1 = c0; }
        *(uint4*)&xs[((rt * 4 + kb) * 64 + q0 * 16 + rl) * 8]       = c0;
        *(uint4*)&xs[((rt * 4 + kb) * 64 + (q0 + 1) * 16 + rl) * 8] = c1;
    }
    __syncthreads();
    int w = tid >> 6, lane = tid & 63;
    int rt = w & 1;
    // ---- stage B: spk = v1b-rows @ s2u ; g = gelu(aggr + spk) -> xf ----
    {
        bf16x8 afr[4];
        #pragma unroll
        for (int kb = 0; kb < 4; kb++)
            afr[kb] = as_bf16x8(*(const uint4*)&xs[((rt * 4 + kb) * 64 + lane) * 8]);
        for (int ct = (w >> 1); ct < 8; ct += 2) {
            const uint4* bp = (const uint4*)(Wall + (((size_t)11 * 8 + ct) * 4) * 512); // t=0, m=11
            f32x4 acc = {0.f, 0.f, 0.f, 0.f};
            #pragma unroll
            for (int kb = 0; kb < 4; kb++) {
                bf16x8 bfr = as_bf16x8(bp[kb * 64 + lane]);
                acc = __builtin_amdgcn_mfma_f32_16x16x32_bf16(afr[kb], bfr, acc, 0, 0, 0);
            }
            int col = ct * 16 + (lane & 15);
            int rbase = rt * 16 + (lane >> 4) * 4;
            #pragma unroll
            for (int r = 0; r < 4; r++) {
                int grow = rbase + r;
                if (grow >= cnt) continue;
                int node = nodes[grow];
                float g = aggr[(size_t)node * ND + col] + acc[r];
                g = 0.5f * g * (1.f + erff(g * 0.70710678118f));
                xf[grow * 132 + col] = g;
            }
        }
    }
    __syncthreads();
    // ---- stage C: repack gelu'd tile into A-frag layout ----
    {
        int row = tid >> 3;
        int d0 = (tid & 7) * 16;
        int rt2 = row >> 4, rl = row & 15;
        int kb = d0 >> 5, q0 = (d0 >> 3) & 3;
        uint4 c0, c1;
        if (row < cnt) {
            const float4* xp4 = (const float4*)(xf + row * 132 + d0);
            float4 a = xp4[0], b2 = xp4[1], c2 = xp4[2], d4 = xp4[3];
            c0.x = pk2(a.x, a.y);   c0.y = pk2(a.z, a.w);
            c0.z = pk2(b2.x, b2.y); c0.w = pk2(b2.z, b2.w);
            c1.x = pk2(c2.x, c2.y); c1.y = pk2(c2.z, c2.w);
            c1.z = pk2(d4.x, d4.y); c1.w = pk2(d4.z, d4.w);
        } else {
            c0.x = c0.y = c0.z = c0.w = 0u;
            c1 = c0;
        }
        *(uint4*)&xs[((rt2 * 4 + kb) * 64 + q0 * 16 + rl) * 8]       = c0;
        *(uint4*)&xs[((rt2 * 4 + kb) * 64 + (q0 + 1) * 16 + rl) * 8] = c1;
    }
    __syncthreads();
    // ---- stage D: out = (g @ Aw[t] + Ab[t]) * alpha + x_in * (1-alpha) ----
    float alpha = 1.f / (1.f + expf(-skip[t]));
    {
        bf16x8 afr[4];
        #pragma unroll
        for (int kb = 0; kb < 4; kb++)
            afr[kb] = as_bf16x8(*(const uint4*)&xs[((rt * 4 + kb) * 64 + lane) * 8]);
        for (int ct = (w >> 1); ct < 8; ct += 2) {
            const uint4* bp = (const uint4*)(Wall + ((((size_t)t * NMAT + 10) * 8 + ct) * 4) * 512);
            f32x4 acc = {0.f, 0.f, 0.f, 0.f};
            #pragma unroll
            for (int kb = 0; kb < 4; kb++) {
                bf16x8 bfr = as_bf16x8(bp[kb * 64 + lane]);
                acc = __builtin_amdgcn_mfma_f32_16x16x32_bf16(afr[kb], bfr, acc, 0, 0, 0);
            }
            int col = ct * 16 + (lane & 15);
            float bias = bcat[(t * NMAT + 10) * ND + col];
            int rbase = rt * 16 + (lane >> 4) * 4;
            #pragma unroll
            for (int r = 0; r < 4; r++) {
                int grow = rbase + r;
                if (grow >= cnt) continue;
                int node = nodes[grow];
                float xin = x_in[(size_t)node * ND + col];
                out[(size_t)node * ND + col] = (acc[r] + bias) * alpha + xin * (1.f - alpha);
            }
        }
    }
}

// Tier-B: fused logits + online segment softmax, wave per target node.
__global__ void __launch_bounds__(256) k_attmd(
    int n, const int* off, const int* srp, const int* ntype,
    const ushort_t* qn, const ushort_t* kt, const float* r_pri,
    float* atts, ushort_t* mb, float* db)
{
    int wv = threadIdx.x >> 6, lane = threadIdx.x & 63;
    int i = blockIdx.x * 4 + wv;
    if (i >= n) return;
    int h = lane & 7, slot = lane >> 3;
    int tt = ntype[i];
    float qf[16];
    load_bf8(qn + (size_t)i * ND + h * DKK, qf);
    load_bf8(qn + (size_t)i * ND + h * DKK + 8, qf + 8);
    const float* prib = r_pri + (size_t)(tt * NR * NT) * NH + h;
    int d0 = off[i], d1 = off[i + 1];
    float m = -3.0e38f, den = 0.f;
    #pragma unroll 2
    for (int p0 = d0; p0 < d1; p0 += 8) {
        int p = p0 + slot;
        bool live = (p < d1);
        int sp = live ? srp[p] : 0;
        int sr = sp & 0x0fffffff;
        int st = ((unsigned int)sp) >> 28;
        int r = sr & (NR - 1);
        float kf[16];
        const ushort_t* kp = kt + (size_t)sr * ND + h * DKK;
        load_bf8(kp, kf);
        load_bf8(kp + 8, kf + 8);
        float a = 0.f;
        #pragma unroll
        for (int f = 0; f < 16; f++) a += qf[f] * kf[f];
        float pri = prib[(r * NT + st) * NH];
        float logit = fminf(fmaxf(a * pri * 0.25f, -1.0e4f), 1.0e4f);
        if (live) {
            atts[(size_t)p * NH + h] = logit;
            float mnew = fmaxf(m, logit);
            den = den * expf(m - mnew) + expf(logit - mnew);
            m = mnew;
        }
    }
    #pragma unroll
    for (int d = 8; d < 64; d <<= 1) {
        float mo = __shfl_xor(m, d, 64);
        float dn = __shfl_xor(den, d, 64);
        float mnew = fmaxf(m, mo);
        den = den * expf(m - mnew) + dn * expf(mo - mnew);
        m = mnew;
    }
    if (slot == 0) {
        ushort_t mh = (d1 > d0) ? f2bf(m) : (ushort_t)0;
        float dfin = (d1 > d0) ? den * expf(m - bf2f(mh)) : 0.f;
        mb[i * NH + h] = mh;
        db[i * NH + h] = dfin;
    }
}

// Tier-B: wave-per-node aggregation; softmax normalize folded in
__global__ void __launch_bounds__(256) k_aggr_fast(
    int n, const int* off, const int* srp, const ushort_t* vt, const float* atts,
    const ushort_t* mb, const float* db, float* aggr)
{
    int wv = threadIdx.x >> 6, lane = threadIdx.x & 63;
    int i = blockIdx.x * 4 + wv;
    if (i >= n) return;
    int h = lane >> 3;
    float mref = bf2f(mb[i * NH + h]);
    float inv = 1.f / (db[i * NH + h] + 1e-16f);
    int d0 = off[i], d1 = off[i + 1];
    float acc0 = 0.f, acc1 = 0.f;
    #pragma unroll 4
    for (int p = d0; p < d1; p++) {
        int sr = srp[p] & 0x0fffffff;
        float w = expf(atts[(size_t)p * NH + h] - mref) * inv;
        unsigned int u = *reinterpret_cast<const unsigned int*>(
            vt + (size_t)sr * ND + lane * 2);
        acc0 += w * bf2f(u & 0xffff);
        acc1 += w * bf2f(u >> 16);
    }
    float2 o; o.x = acc0; o.y = acc1;
    *reinterpret_cast<float2*>(aggr + (size_t)i * ND + lane * 2) = o;
}

// ================= FALLBACK PATH (proven kernels) =================

__global__ void k_proj(int n, const float* x_in, const int* ntype, const int* order,
                       const float* Kw, const float* Kb,
                       const float* Qw, const float* Qb,
                       const float* Vw, const float* Vb,
                       ushort_t* kn, ushort_t* qn, ushort_t* vn, ushort_t* v1) {
    __shared__ float xs[NB][ND];
    __shared__ int nodes[NB];
    __shared__ int types[NB];
    int tid = threadIdx.x;
    int base = blockIdx.x * NB;
    int cnt = min(NB, n - base);
    if (tid < cnt) { int nd = order[base + tid]; nodes[tid] = nd; types[tid] = ntype[nd]; }
    __syncthreads();
    for (int j = 0; j < cnt; j++) xs[j][tid] = x_in[(size_t)nodes[j] * ND + tid];
    __syncthreads();
    bool uni = (types[0] == types[cnt - 1]);
    for (int m = 0; m < 4; m++) {
        const float *W, *B; ushort_t* out; int forced_t = -1;
        if (m == 0)      { W = Kw; B = Kb; out = kn; }
        else if (m == 1) { W = Qw; B = Qb; out = qn; }
        else if (m == 2) { W = Vw; B = Vb; out = vn; }
        else             { W = Vw; B = Vb; out = v1; forced_t = 1; }
        if (uni || forced_t >= 0) {
            int t = (forced_t >= 0) ? forced_t : types[0];
            float bias = B[t * ND + tid];
            float acc[NB];
            #pragma unroll
            for (int j = 0; j < NB; j++) acc[j] = bias;
            const float* Wp = W + (size_t)t * ND * ND + tid;
            for (int d = 0; d < ND; d++) {
                float w = Wp[(size_t)d * ND];
                #pragma unroll
                for (int j = 0; j < NB; j++) acc[j] += xs[j][d] * w;
            }
            for (int j = 0; j < cnt; j++) out[(size_t)nodes[j] * ND + tid] = f2bf(acc[j]);
        } else {
            for (int j = 0; j < cnt; j++) {
                int t = types[j];
                float acc = B[t * ND + tid];
                const float* Wp = W + (size_t)t * ND * ND + tid;
                for (int d = 0; d < ND; d++) acc += xs[j][d] * Wp[(size_t)d * ND];
                out[(size_t)nodes[j] * ND + tid] = f2bf(acc);
            }
        }
    }
}

__global__ void k_att(int e, const int* src, const int* tgt, const int* etype, const int* ntype,
                      const ushort_t* kn, const ushort_t* qn,
                      const float* r_att, const float* r_pri, float* att) {
    int id = blockIdx.x * 256 + threadIdx.x;
    if (id >= e * NH) return;
    int ee = id >> 3, h = id & 7;
    int s = src[ee], t = tgt[ee], r = etype[ee];
    float kf[16], qf[16];
    load_bf8(kn + (size_t)s * ND + h * DKK, kf);
    load_bf8(kn + (size_t)s * ND + h * DKK + 8, kf + 8);
    load_bf8(qn + (size_t)t * ND + h * DKK, qf);
    load_bf8(qn + (size_t)t * ND + h * DKK + 8, qf + 8);
    const float* W = r_att + (size_t)(r * NH + h) * DKK * DKK;
    float kt[16];
    #pragma unroll
    for (int f = 0; f < 16; f++) kt[f] = 0.f;
    #pragma unroll 4
    for (int d = 0; d < 16; d++) {
        float kd = kf[d];
        #pragma unroll
        for (int f = 0; f < 16; f++) kt[f] += kd * W[d * 16 + f];
    }
    float a = 0.f;
    #pragma unroll
    for (int f = 0; f < 16; f++) a += qf[f] * kt[f];
    int tt = ntype[t], st = ntype[s];
    float pri = r_pri[((tt * NR + r) * NT + st) * NH + h];
    float logit = a * pri * 0.25f;
    logit = fminf(fmaxf(logit, -1.0e4f), 1.0e4f);
    att[(size_t)ee * NH + h] = logit;
}

__global__ void k_mden(int n, const int* off, const int* sorted,
                       const float* att, ushort_t* mb, float* db) {
    int id = blockIdx.x * 256 + threadIdx.x;
    if (id >= n * NH) return;
    int i = id >> 3, h = id & 7;
    int d0 = off[i], d1 = off[i + 1];
    float m = -3.0e38f;
    for (int p = d0; p < d1; p++) m = fmaxf(m, att[(size_t)sorted[p] * NH + h]);
    ushort_t mh = (d1 > d0) ? f2bf(m) : (ushort_t)0;
    float mref = bf2f(mh);
    float den = 0.f;
    for (int p = d0; p < d1; p++) den += expf(att[(size_t)sorted[p] * NH + h] - mref);
    mb[id] = mh;
    db[id] = den;
}

__global__ void k_norm(int e, const int* tgt, const ushort_t* mb, const float* db, float* att) {
    int id = blockIdx.x * 256 + threadIdx.x;
    if (id >= e * NH) return;
    int ee = id >> 3, h = id & 7;
    int t = tgt[ee];
    float w = expf(att[id] - bf2f(mb[t * NH + h])) / (db[t * NH + h] + 1e-16f);
    att[id] = w;
}

__global__ void k_aggr(int n, const int* off, const int* sorted, const int* src, const int* etype,
                       const ushort_t* vn, const float* r_msg, const float* att, float* aggr) {
    int wv = threadIdx.x >> 6, lane = threadIdx.x & 63;
    int i = blockIdx.x * 4 + wv;
    if (i >= n) return;
    int h = lane >> 3, f0 = (lane & 7) * 2;
    int d0 = off[i], d1 = off[i + 1];
    float acc0 = 0.f, acc1 = 0.f;
    for (int p = d0; p < d1; p++) {
        int ee = sorted[p];
        int s = src[ee], r = etype[ee];
        float w = att[(size_t)ee * NH + h];
        float vj[16];
        load_bf8(vn + (size_t)s * ND + h * DKK, vj);
        load_bf8(vn + (size_t)s * ND + h * DKK + 8, vj + 8);
        const float* Wm = r_msg + (size_t)(r * NH + h) * DKK * DKK + f0;
        float a0 = 0.f, a1 = 0.f;
        #pragma unroll
        for (int d = 0; d < 16; d++) {
            a0 += vj[d] * Wm[d * 16];
            a1 += vj[d] * Wm[d * 16 + 1];
        }
        acc0 += w * a0; acc1 += w * a1;
    }
    aggr[(size_t)i * ND + h * DKK + f0]     = acc0;
    aggr[(size_t)i * ND + h * DKK + f0 + 1] = acc1;
}

__global__ void k_spk(int n, const int* winner, const int* tgt, const ushort_t* v1,
                      const float* s2u, float* aggr) {
    __shared__ float xs[NB][ND];
    __shared__ int wn[NB];
    int tid = threadIdx.x;
    int base = blockIdx.x * NB;
    int cnt = min(NB, n - base);
    if (tid < cnt) wn[tid] = winner[base + tid];
    __syncthreads();
    for (int j = 0; j < cnt; j++) {
        int w = wn[j];
        xs[j][tid] = (w >= 0) ? bf2f(v1[(size_t)tgt[w] * ND + tid]) : 0.f;
    }
    __syncthreads();
    float acc[NB];
    #pragma unroll
    for (int j = 0; j < NB; j++) acc[j] = 0.f;
    const float* Wp = s2u + tid;
    for (int d = 0; d < ND; d++) {
        float w = Wp[(size_t)d * ND];
        #pragma unroll
        for (int j = 0; j < NB; j++) acc[j] += xs[j][d] * w;
    }
    for (int j = 0; j < cnt; j++) {
        size_t idx = (size_t)(base + j) * ND + tid;
        float g = aggr[idx] + acc[j];
        g = 0.5f * g * (1.f + erff(g * 0.70710678118f));
        aggr[idx] = g;
    }
}

__global__ void k_final(int n, const float* x_in, const int* ntype, const int* order,
                        const float* Aw, const float* Ab, const float* skip,
                        const float* aggr, float* out) {
    __shared__ float xs[NB][ND];
    __shared__ int nodes[NB];
    __shared__ int types[NB];
    int tid = threadIdx.x;
    int base = blockIdx.x * NB;
    int cnt = min(NB, n - base);
    if (tid < cnt) { int nd = order[base + tid]; nodes[tid] = nd; types[tid] = ntype[nd]; }
    __syncthreads();
    for (int j = 0; j < cnt; j++) xs[j][tid] = aggr[(size_t)nodes[j] * ND + tid];
    __syncthreads();
    bool uni = (types[0] == types[cnt - 1]);
    if (uni) {
        int t = types[0];
        float bias = Ab[t * ND + tid];
        float acc[NB];
        #pragma unroll
        for (int j = 0; j < NB; j++) acc[j] = bias;
        const float* Wp = Aw + (size_t)t * ND * ND + tid;
        for (int d = 0; d < ND; d++) {
            float w = Wp[(size_t)d * ND];
            #pragma unroll
            for (int j = 0; j < NB; j++) acc[j] += xs[j][d] * w;
        }
        float alpha = 1.f / (1.f + expf(-skip[t]));
        for (int j = 0; j < cnt; j++) {
            float xin = x_in[(size_t)nodes[j] * ND + tid];
            out[(size_t)nodes[j] * ND + tid] = acc[j] * alpha + xin * (1.f - alpha);
        }
    } else {
        for (int j = 0; j < cnt; j++) {
            int t = types[j];
            float acc = Ab[t * ND + tid];
            const float* Wp = Aw + (size_t)t * ND * ND + tid;
            for (int d = 0; d < ND; d++) acc += xs[j][d] * Wp[(size_t)d * ND];
            float alpha = 1.f / (1.f + expf(-skip[t]));
            float xin = x_in[(size_t)nodes[j] * ND + tid];
            out[(size_t)nodes[j] * ND + tid] = acc * alpha + xin * (1.f - alpha);
        }
    }
}

extern "C" void kernel_launch(void* const* d_in, const int* in_sizes, int n_in,
                              void* d_out, int out_size, void* d_ws, size_t ws_size,
                              hipStream_t stream) {
    const float* node_inp = (const float*)d_in[0];
    const int* node_type  = (const int*)d_in[1];
    const int* edge_index = (const int*)d_in[2];
    const int* edge_type  = (const int*)d_in[3];
    const float* Kw = (const float*)d_in[5];
    const float* Kb = (const float*)d_in[6];
    const float* Qw = (const float*)d_in[7];
    const float* Qb = (const float*)d_in[8];
    const float* Vw = (const float*)d_in[9];
    const float* Vb = (const float*)d_in[10];
    const float* Aw = (const float*)d_in[11];
    const float* Ab = (const float*)d_in[12];
    const float* r_pri = (const float*)d_in[13];
    const float* r_att = (const float*)d_in[14];
    const float* r_msg = (const float*)d_in[15];
    const float* s2u   = (const float*)d_in[16];
    const float* skip  = (const float*)d_in[17];

    int n = in_sizes[1];
    int e = in_sizes[3];
    const int* srcp = edge_index;
    const int* tgtp = edge_index + e;

    char* wsp = (char*)d_ws;
    size_t woff = 0;
    auto alloc = [&](size_t b) { void* p = wsp + woff; woff += (b + 255) & ~(size_t)255; return p; };

    // ---- common infra ----
    int* offs     = (int*)alloc((size_t)(n + 1) * 4);
    int* winner   = (int*)alloc((size_t)n * 4);
    int* order    = (int*)alloc((size_t)n * 4);
    int* tcnt     = (int*)alloc(16);
    int* tstart   = (int*)alloc(16);
    int* bsum4    = (int*)alloc(4096);
    int* boff4    = (int*)alloc(4096);
    int* eord     = (int*)alloc((size_t)e * 4);   // fast: srp record; fallback: sorted edge id
    ushort_t* mb  = (ushort_t*)alloc((size_t)n * NH * 2);
    float* db     = (float*)alloc((size_t)n * NH * 4);
    ushort_t* v1b = (ushort_t*)alloc((size_t)n * ND * 2);
    float* att    = (float*)alloc((size_t)e * NH * 4);
    size_t commonEnd = woff;

    // rank lives in att's space: written by k_count, dead after k_scatter.
    int* rank = (int*)att;

    // ---- Tier B layout ----
    woff = commonEnd;
    ushort_t* WallB = (ushort_t*)alloc((size_t)NT * NMAT * 8 * 4 * 512 * 2);
    float* bcatB    = (float*)alloc((size_t)NT * NMAT * ND * 4);
    char* F         = (char*)alloc((size_t)n * 1536);   // phase1: qn+kt; phase2: vt+aggr
    size_t fastEnd = woff;

    // ---- Tier A (flash) layout: qn+kt+vt live together; aggr overlays att ----
    woff = commonEnd;
    ushort_t* WallA = (ushort_t*)alloc((size_t)NT * NMAT * 8 * 4 * 512 * 2);
    float* bcatA    = (float*)alloc((size_t)NT * NMAT * ND * 4);
    ushort_t* qnA   = (ushort_t*)alloc((size_t)n * ND * 2);
    ushort_t* ktA   = (ushort_t*)alloc((size_t)n * NR * ND * 2);
    ushort_t* vtA   = (ushort_t*)alloc((size_t)n * NR * ND * 2);
    size_t tierAEnd = woff;
    float* aggrA = (float*)att;   // requires e*NH*4 >= n*ND*4 (equal here); rank dead by then

    int gn = (n + 255) / 256;
    int ge = (e + 255) / 256;
    int nbscan = n / SCB + 1;
    int gproj = (n + 31) / 32 + NT;

    int tierA = (ws_size >= tierAEnd) && ((size_t)e * NH >= (size_t)n * ND);
    int fast  = (ws_size >= fastEnd);

    k_zero<<<gn, 256, 0, stream>>>(n, offs, winner);
    k_count<<<ge, 256, 0, stream>>>(e, srcp, tgtp, edge_type, offs, winner, rank);
    k_scanA<<<nbscan, 256, 0, stream>>>(n, offs, node_type, bsum4);
    k_scanB<<<1, 64, 0, stream>>>(nbscan, bsum4, boff4, tcnt, tstart);
    k_scanC<<<nbscan, 256, 0, stream>>>(n, offs, node_type, boff4, tstart, order);
    k_scatter<<<ge, 256, 0, stream>>>(e, srcp, tgtp, edge_type, node_type, offs, rank,
                                      eord, (tierA || fast) ? 1 : 0);

    if (tierA) {
        // ======== TIER A: single projection + pipelined flash + fused epilogue ========
        k_pack<<<NT * NMAT * 8 * 4, 64, 0, stream>>>(Qw, Qb, Kw, Kb, Vw, Vb, Aw, Ab,
                                                     s2u, r_att, r_msg, WallA, bcatA);
        k_projall<<<gproj, 256, 0, stream>>>(n, node_inp, order, tcnt, tstart, WallA, bcatA,
                                             qnA, ktA, v1b, vtA);
        k_flash<<<(n + 3) / 4, 256, 0, stream>>>(n, offs, eord, node_type,
                                                 qnA, ktA, vtA, r_pri, aggrA);
        k_sfinal<<<gproj, 256, 0, stream>>>(n, node_inp, order, tcnt, tstart,
                                            winner, tgtp, v1b, WallA, bcatA, skip,
                                            aggrA, (float*)d_out);
    } else if (fast) {
        // ======== TIER B ========
        ushort_t* qn  = (ushort_t*)F;
        ushort_t* kt  = (ushort_t*)(F + (size_t)n * 256);
        ushort_t* vt  = (ushort_t*)F;                         // overlays qn+kt (dead after k_attmd)
        float* aggr   = (float*)(F + (size_t)n * 1024);       // overlays kt tail (dead)

        k_pack<<<NT * NMAT * 8 * 4, 64, 0, stream>>>(Qw, Qb, Kw, Kb, Vw, Vb, Aw, Ab,
                                                     s2u, r_att, r_msg, WallB, bcatB);
        k_projm<<<gproj, 256, 0, stream>>>(n, node_inp, order, tcnt, tstart, WallB, bcatB,
                                           0, 6, qn, kt, v1b, (ushort_t*)nullptr);
        k_attmd<<<(n + 3) / 4, 256, 0, stream>>>(n, offs, eord, node_type,
                                                 qn, kt, r_pri, att, mb, db);
        k_projm<<<gproj, 256, 0, stream>>>(n, node_inp, order, tcnt, tstart, WallB, bcatB,
                                           6, 4, (ushort_t*)nullptr, (ushort_t*)nullptr,
                                           (ushort_t*)nullptr, vt);
        k_aggr_fast<<<(n + 3) / 4, 256, 0, stream>>>(n, offs, eord, vt, att, mb, db, aggr);
        k_sfinal<<<gproj, 256, 0, stream>>>(n, node_inp, order, tcnt, tstart,
                                            winner, tgtp, v1b, WallB, bcatB, skip,
                                            aggr, (float*)d_out);
    } else {
        // ======== FALLBACK ========
        woff = commonEnd;
        ushort_t* vn  = (ushort_t*)alloc((size_t)n * ND * 2);
        char* regA    = (char*)alloc((size_t)n * ND * 2 * 2);
        ushort_t* kn  = (ushort_t*)regA;
        ushort_t* qn  = (ushort_t*)(regA + (size_t)n * ND * 2);
        float* aggr   = (float*)regA;

        k_proj<<<(n + NB - 1) / NB, 128, 0, stream>>>(n, node_inp, node_type, order,
                                                      Kw, Kb, Qw, Qb, Vw, Vb, kn, qn, vn, v1b);
        k_att<<<(e * NH + 255) / 256, 256, 0, stream>>>(e, srcp, tgtp, edge_type, node_type,
                                                        kn, qn, r_att, r_pri, att);
        k_mden<<<(n * NH + 255) / 256, 256, 0, stream>>>(n, offs, eord, att, mb, db);
        k_norm<<<(e * NH + 255) / 256, 256, 0, stream>>>(e, tgtp, mb, db, att);
        k_aggr<<<(n + 3) / 4, 256, 0, stream>>>(n, offs, eord, srcp, edge_type, vn, r_msg, att, aggr);
        k_spk<<<(n + NB - 1) / NB, 128, 0, stream>>>(n, winner, tgtp, v1b, s2u, aggr);
        k_final<<<(n + NB - 1) / NB, 128, 0, stream>>>(n, node_inp, node_type, order,
                                                       Aw, Ab, skip, aggr, (float*)d_out);
    }
}

// Round 14
// 312.131 us; speedup vs baseline: 1.0571x; 1.0036x over previous
//
#include <hip/hip_runtime.h>
#include <hip/hip_bf16.h>
#include <math.h>

#define ND 128
#define NH 8
#define DKK 16
#define NT 3
#define NR 4
#define NB 8
#define NMAT 12   // pack: 0=Q, 1..4=K@att[r], 5=V(type1), 6..9=V@msg[r], 10=A, 11=s2u
#define SCB 4096  // scan elems per block (256 threads x 16)

typedef unsigned short ushort_t;
typedef __bf16 bf16_t;
typedef bf16_t bf16x8 __attribute__((ext_vector_type(8)));
typedef float f32x4 __attribute__((ext_vector_type(4)));

__device__ __forceinline__ float bf2f(unsigned short u) {
    union { unsigned int i; float f; } v; v.i = ((unsigned int)u) << 16; return v.f;
}
__device__ __forceinline__ unsigned short f2bf(float f) {
    union { float f; unsigned int i; } v; v.f = f;
    unsigned int x = v.i;
    unsigned int lsb = (x >> 16) & 1u;
    x += 0x7fffu + lsb;
    return (unsigned short)(x >> 16);
}
__device__ __forceinline__ unsigned int pk2(float a, float b) {
    return (unsigned int)f2bf(a) | ((unsigned int)f2bf(b) << 16);
}
__device__ __forceinline__ void load_bf8(const ushort_t* p, float* o) {
    uint4 u = *reinterpret_cast<const uint4*>(p);
    o[0]=bf2f(u.x & 0xffff); o[1]=bf2f(u.x >> 16);
    o[2]=bf2f(u.y & 0xffff); o[3]=bf2f(u.y >> 16);
    o[4]=bf2f(u.z & 0xffff); o[5]=bf2f(u.z >> 16);
    o[6]=bf2f(u.w & 0xffff); o[7]=bf2f(u.w >> 16);
}
__device__ __forceinline__ void cvt8(uint4 u, float* o) {
    o[0]=bf2f(u.x & 0xffff); o[1]=bf2f(u.x >> 16);
    o[2]=bf2f(u.y & 0xffff); o[3]=bf2f(u.y >> 16);
    o[4]=bf2f(u.z & 0xffff); o[5]=bf2f(u.z >> 16);
    o[6]=bf2f(u.w & 0xffff); o[7]=bf2f(u.w >> 16);
}
__device__ __forceinline__ bf16x8 as_bf16x8(uint4 u) {
    union { uint4 u; bf16x8 v; } c; c.u = u; return c.v;
}

// ---------------- sort / bucket infrastructure ----------------

__global__ void k_zero(int n, int* offs, int* winner) {
    int i = blockIdx.x * 256 + threadIdx.x;
    if (i < n) { offs[i] = 0; winner[i] = -1; }
}

// Edge counting: the atomicAdd RETURN VALUE is the edge's rank within its
// target bucket -> k_scatter needs no atomics.
__global__ void k_count(int e, const int* src, const int* tgt, const int* etype,
                        int* offs, int* winner, int* rank) {
    int i = blockIdx.x * 256 + threadIdx.x;
    if (i < e) {
        rank[i] = atomicAdd(&offs[tgt[i]], 1);
        if (etype[i] == 0) atomicMax(&winner[src[i]], i);  // last-write-wins == max edge id
    }
}

// ---- multi-block scan: offs prefix AND stable 3-way type partition ----
// bsum4/boff4: per block [offs_sum, cnt_t0, cnt_t1, cnt_t2]

__global__ void k_scanA(int n, const int* offs, const int* ntype, int* bsum4) {
    __shared__ int red[256];
    __shared__ int tr[256][3];
    int b = blockIdx.x, tid = threadIdx.x;
    int base = b * SCB + tid * 16;
    int s = 0, c0 = 0, c1 = 0, c2 = 0;
    #pragma unroll
    for (int i = 0; i < 16; i++) {
        int idx = base + i;
        if (idx < n) {
            s += offs[idx];
            int t = ntype[idx];
            c0 += (t == 0); c1 += (t == 1); c2 += (t == 2);
        }
    }
    red[tid] = s; tr[tid][0] = c0; tr[tid][1] = c1; tr[tid][2] = c2;
    __syncthreads();
    for (int d = 128; d > 0; d >>= 1) {
        if (tid < d) {
            red[tid] += red[tid + d];
            tr[tid][0] += tr[tid + d][0];
            tr[tid][1] += tr[tid + d][1];
            tr[tid][2] += tr[tid + d][2];
        }
        __syncthreads();
    }
    if (tid == 0) {
        bsum4[b * 4]     = red[0];
        bsum4[b * 4 + 1] = tr[0][0];
        bsum4[b * 4 + 2] = tr[0][1];
        bsum4[b * 4 + 3] = tr[0][2];
    }
}

__global__ void k_scanB(int nb, const int* bsum4, int* boff4, int* tcnt, int* tstart) {
    if (threadIdx.x == 0) {
        int run = 0, r0 = 0, r1 = 0, r2 = 0;
        for (int b = 0; b < nb; b++) {
            boff4[b * 4]     = run;
            boff4[b * 4 + 1] = r0;
            boff4[b * 4 + 2] = r1;
            boff4[b * 4 + 3] = r2;
            run += bsum4[b * 4];
            r0  += bsum4[b * 4 + 1];
            r1  += bsum4[b * 4 + 2];
            r2  += bsum4[b * 4 + 3];
        }
        tcnt[0] = r0; tcnt[1] = r1; tcnt[2] = r2;
        tstart[0] = 0; tstart[1] = r0; tstart[2] = r0 + r1;
    }
}

// offs -> exclusive prefix; order -> STABLE type partition (ascending node id
// within each type segment): sequential-row access for all tile kernels.
__global__ void k_scanC(int n, int* offs, const int* ntype, const int* boff4,
                        const int* tstart, int* order) {
    __shared__ int red[256];
    __shared__ int tr[256][3];
    int b = blockIdx.x, tid = threadIdx.x;
    int base = b * SCB + tid * 16;
    int v[16]; signed char ty[16];
    int s = 0, c0 = 0, c1 = 0, c2 = 0;
    #pragma unroll
    for (int i = 0; i < 16; i++) {
        int idx = base + i;
        v[i] = (idx < n) ? offs[idx] : 0;
        s += v[i];
        int t = (idx < n) ? ntype[idx] : -1;
        ty[i] = (signed char)t;
        c0 += (t == 0); c1 += (t == 1); c2 += (t == 2);
    }
    red[tid] = s; tr[tid][0] = c0; tr[tid][1] = c1; tr[tid][2] = c2;
    __syncthreads();
    for (int d = 1; d < 256; d <<= 1) {
        int vv = (tid >= d) ? red[tid - d] : 0;
        int w0 = (tid >= d) ? tr[tid - d][0] : 0;
        int w1 = (tid >= d) ? tr[tid - d][1] : 0;
        int w2 = (tid >= d) ? tr[tid - d][2] : 0;
        __syncthreads();
        red[tid] += vv; tr[tid][0] += w0; tr[tid][1] += w1; tr[tid][2] += w2;
        __syncthreads();
    }
    int run = boff4[b * 4] + red[tid] - s;          // exclusive offs prefix
    int p0 = tstart[0] + boff4[b * 4 + 1] + tr[tid][0] - c0;
    int p1 = tstart[1] + boff4[b * 4 + 2] + tr[tid][1] - c1;
    int p2 = tstart[2] + boff4[b * 4 + 3] + tr[tid][2] - c2;
    #pragma unroll
    for (int i = 0; i < 16; i++) {
        int idx = base + i;
        if (idx < n) {
            offs[idx] = run; run += v[i];
            int t = ty[i];
            if (t == 0)      order[p0++] = idx;
            else if (t == 1) order[p1++] = idx;
            else             order[p2++] = idx;
        }
    }
    if (base <= n && n < base + 16) offs[n] = run;   // grand total
}

// ATOMIC-FREE edge scatter: slot = scanned offs + precomputed rank.
// mode=1: eord[p] = (src*NR+etype) | ntype[src]<<28 ; mode=0: eord[p] = edge id
__global__ void k_scatter(int e, const int* src, const int* tgt, const int* etype,
                          const int* ntype, const int* offs, const int* rank,
                          int* eord, int mode) {
    int i = blockIdx.x * 256 + threadIdx.x;
    if (i < e) {
        int p = offs[tgt[i]] + rank[i];
        if (mode) {
            int s = src[i];
            eord[p] = (s * NR + etype[i]) | (ntype[s] << 28);
        } else {
            eord[p] = i;
        }
    }
}

// ================= PACK (12 mats, proven) =================

__global__ void k_pack(const float* Qw, const float* Qb, const float* Kw, const float* Kb,
                       const float* Vw, const float* Vb, const float* Aw, const float* Ab,
                       const float* s2u, const float* r_att, const float* r_msg,
                       ushort_t* Wall, float* bcat) {
    int blk = blockIdx.x;
    int kb = blk & 3;
    int c = (blk >> 2) & 7;
    int tm = blk >> 5;
    int m = tm % NMAT, t = tm / NMAT;
    int lane = threadIdx.x;
    int nn = c * 16 + (lane & 15);
    int quad = lane >> 4;
    int k0 = kb * 32 + quad * 8;
    ushort_t* dst = Wall + (size_t)blk * 512 + lane * 8;

    if (m == 0 || m == 5 || m == 10 || m == 11) {
        const float* W; const float* B;
        if (m == 0)       { W = Qw + (size_t)t * ND * ND; B = Qb + t * ND; }
        else if (m == 5)  { W = Vw + (size_t)ND * ND;     B = Vb + ND; }
        else if (m == 10) { W = Aw + (size_t)t * ND * ND; B = Ab + t * ND; }
        else              { W = s2u;                      B = nullptr; }
        #pragma unroll
        for (int j = 0; j < 8; j++) dst[j] = f2bf(W[(size_t)(k0 + j) * ND + nn]);
        if (kb == 0 && quad == 0)
            bcat[(t * NMAT + m) * ND + nn] = B ? B[nn] : 0.f;
    } else {
        int r = (m <= 4) ? (m - 1) : (m - 6);
        const float* W0 = (m <= 4) ? Kw : Vw;
        const float* B0 = (m <= 4) ? Kb : Vb;
        const float* Wr = (m <= 4) ? r_att : r_msg;
        int h = c, f = lane & 15;
        float wcol[16];
        #pragma unroll
        for (int jj = 0; jj < 16; jj++)
            wcol[jj] = Wr[(((size_t)r * NH + h) * DKK + jj) * DKK + f];
        #pragma unroll
        for (int j = 0; j < 8; j++) {
            const float* row = W0 + ((size_t)t * ND + (k0 + j)) * ND + h * DKK;
            float s = 0.f;
            #pragma unroll
            for (int jj = 0; jj < 16; jj++) s += row[jj] * wcol[jj];
            dst[j] = f2bf(s);
        }
        if (kb == 0 && quad == 0) {
            const float* brow = B0 + t * ND + h * DKK;
            float sb = 0.f;
            #pragma unroll
            for (int jj = 0; jj < 16; jj++) sb += brow[jj] * wcol[jj];
            bcat[(t * NMAT + m) * ND + nn] = sb;
        }
    }
}

// Tier-B projection, mats [m0, m0+nm)
__global__ void __launch_bounds__(256) k_projm(
    int n, const float* x_in, const int* order,
    const int* tcnt, const int* tstart,
    const ushort_t* Wall, const float* bcat,
    int m0, int nm,
    ushort_t* out_qn, ushort_t* out_kt, ushort_t* out_v1, ushort_t* out_vt)
{
    __shared__ __align__(16) ushort_t xs[4096];
    __shared__ int nodes[32];
    int b = blockIdx.x;
    int nb0 = (tcnt[0] + 31) >> 5, nb1 = (tcnt[1] + 31) >> 5, nb2 = (tcnt[2] + 31) >> 5;
    int t, lb;
    if (b < nb0)                  { t = 0; lb = b; }
    else if (b < nb0 + nb1)       { t = 1; lb = b - nb0; }
    else if (b < nb0 + nb1 + nb2) { t = 2; lb = b - nb0 - nb1; }
    else return;
    int segoff = lb * 32;
    int cnt = min(32, tcnt[t] - segoff);
    int segbase = tstart[t] + segoff;
    int tid = threadIdx.x;
    if (tid < 32) nodes[tid] = (tid < cnt) ? order[segbase + tid] : -1;
    __syncthreads();
    {
        int row = tid >> 3;
        int d0 = (tid & 7) * 16;
        int rt = row >> 4, rl = row & 15;
        int kb = d0 >> 5, q0 = (d0 >> 3) & 3;
        uint4 c0, c1;
        if (row < cnt) {
            const float4* xp4 = (const float4*)(x_in + (size_t)nodes[row] * ND + d0);
            float4 a = xp4[0], b2 = xp4[1], c2 = xp4[2], d4 = xp4[3];
            c0.x = pk2(a.x, a.y);   c0.y = pk2(a.z, a.w);
            c0.z = pk2(b2.x, b2.y); c0.w = pk2(b2.z, b2.w);
            c1.x = pk2(c2.x, c2.y); c1.y = pk2(c2.z, c2.w);
            c1.z = pk2(d4.x, d4.y); c1.w = pk2(d4.z, d4.w);
        } else {
            c0.x = c0.y = c0.z = c0.w = 0u;
            c1 = c0;
        }
        *(uint4*)&xs[((rt * 4 + kb) * 64 + q0 * 16 + rl) * 8]       = c0;
        *(uint4*)&xs[((rt * 4 + kb) * 64 + (q0 + 1) * 16 + rl) * 8] = c1;
    }
    __syncthreads();

    int w = tid >> 6, lane = tid & 63;
    int rt = w & 1;
    bf16x8 afr[4];
    #pragma unroll
    for (int kb = 0; kb < 4; kb++)
        afr[kb] = as_bf16x8(*(const uint4*)&xs[((rt * 4 + kb) * 64 + lane) * 8]);
    int nct = nm * 8;
    for (int ct = (w >> 1); ct < nct; ct += 2) {
        int m = m0 + (ct >> 3), c = ct & 7;
        const uint4* bp = (const uint4*)(Wall + ((((size_t)t * NMAT + m) * 8 + c) * 4) * 512);
        f32x4 acc = {0.f, 0.f, 0.f, 0.f};
        #pragma unroll
        for (int kb = 0; kb < 4; kb++) {
            bf16x8 bfr = as_bf16x8(bp[kb * 64 + lane]);
            acc = __builtin_amdgcn_mfma_f32_16x16x32_bf16(afr[kb], bfr, acc, 0, 0, 0);
        }
        int col = c * 16 + (lane & 15);
        float bias = bcat[(t * NMAT + m) * ND + col];
        int rbase = rt * 16 + (lane >> 4) * 4;
        #pragma unroll
        for (int r = 0; r < 4; r++) {
            int grow = rbase + r;
            if (grow >= cnt) continue;
            int node = nodes[grow];
            ushort_t val = f2bf(acc[r] + bias);
            if (m == 0)       out_qn[(size_t)node * ND + col] = val;
            else if (m <= 4)  out_kt[((size_t)node * NR + (m - 1)) * ND + col] = val;
            else if (m == 5)  out_v1[(size_t)node * ND + col] = val;
            else              out_vt[((size_t)node * NR + (m - 6)) * ND + col] = val;
        }
    }
}

// Tier-A projection: all mats 0..9 in ONE launch (x staged once).
__global__ void __launch_bounds__(256) k_projall(
    int n, const float* x_in, const int* order,
    const int* tcnt, const int* tstart,
    const ushort_t* Wall, const float* bcat,
    ushort_t* out_qn, ushort_t* out_kt, ushort_t* out_v1, ushort_t* out_vt)
{
    __shared__ __align__(16) ushort_t xs[4096];
    __shared__ int nodes[32];
    int b = blockIdx.x;
    int nb0 = (tcnt[0] + 31) >> 5, nb1 = (tcnt[1] + 31) >> 5, nb2 = (tcnt[2] + 31) >> 5;
    int t, lb;
    if (b < nb0)                  { t = 0; lb = b; }
    else if (b < nb0 + nb1)       { t = 1; lb = b - nb0; }
    else if (b < nb0 + nb1 + nb2) { t = 2; lb = b - nb0 - nb1; }
    else return;
    int segoff = lb * 32;
    int cnt = min(32, tcnt[t] - segoff);
    int segbase = tstart[t] + segoff;
    int tid = threadIdx.x;
    if (tid < 32) nodes[tid] = (tid < cnt) ? order[segbase + tid] : -1;
    __syncthreads();
    {
        int row = tid >> 3;
        int d0 = (tid & 7) * 16;
        int rt = row >> 4, rl = row & 15;
        int kb = d0 >> 5, q0 = (d0 >> 3) & 3;
        uint4 c0, c1;
        if (row < cnt) {
            const float4* xp4 = (const float4*)(x_in + (size_t)nodes[row] * ND + d0);
            float4 a = xp4[0], b2 = xp4[1], c2 = xp4[2], d4 = xp4[3];
            c0.x = pk2(a.x, a.y);   c0.y = pk2(a.z, a.w);
            c0.z = pk2(b2.x, b2.y); c0.w = pk2(b2.z, b2.w);
            c1.x = pk2(c2.x, c2.y); c1.y = pk2(c2.z, c2.w);
            c1.z = pk2(d4.x, d4.y); c1.w = pk2(d4.z, d4.w);
        } else {
            c0.x = c0.y = c0.z = c0.w = 0u;
            c1 = c0;
        }
        *(uint4*)&xs[((rt * 4 + kb) * 64 + q0 * 16 + rl) * 8]       = c0;
        *(uint4*)&xs[((rt * 4 + kb) * 64 + (q0 + 1) * 16 + rl) * 8] = c1;
    }
    __syncthreads();

    int w = tid >> 6, lane = tid & 63;
    int rt = w & 1;
    bf16x8 afr[4];
    #pragma unroll
    for (int kb = 0; kb < 4; kb++)
        afr[kb] = as_bf16x8(*(const uint4*)&xs[((rt * 4 + kb) * 64 + lane) * 8]);
    for (int ct = (w >> 1); ct < 80; ct += 2) {   // mats 0..9
        int m = ct >> 3, c = ct & 7;
        const uint4* bp = (const uint4*)(Wall + ((((size_t)t * NMAT + m) * 8 + c) * 4) * 512);
        f32x4 acc = {0.f, 0.f, 0.f, 0.f};
        #pragma unroll
        for (int kb = 0; kb < 4; kb++) {
            bf16x8 bfr = as_bf16x8(bp[kb * 64 + lane]);
            acc = __builtin_amdgcn_mfma_f32_16x16x32_bf16(afr[kb], bfr, acc, 0, 0, 0);
        }
        int col = c * 16 + (lane & 15);
        float bias = bcat[(t * NMAT + m) * ND + col];
        int rbase = rt * 16 + (lane >> 4) * 4;
        #pragma unroll
        for (int r = 0; r < 4; r++) {
            int grow = rbase + r;
            if (grow >= cnt) continue;
            int node = nodes[grow];
            ushort_t val = f2bf(acc[r] + bias);
            if (m == 0)       out_qn[(size_t)node * ND + col] = val;
            else if (m <= 4)  out_kt[((size_t)node * NR + (m - 1)) * ND + col] = val;
            else if (m == 5)  out_v1[(size_t)node * ND + col] = val;
            else              out_vt[((size_t)node * NR + (m - 6)) * ND + col] = val;
        }
    }
}

// Tier-A: fused flash attention + aggregation, one pass over edges per node.
// 2-deep software pipeline: stage next chunk's srp + raw K row during current
// chunk's compute; issue current chunk's V words before the shfl reductions.
__global__ void __launch_bounds__(256) k_flash(
    int n, const int* off, const int* srp, const int* ntype,
    const ushort_t* qn, const ushort_t* kt, const ushort_t* vt,
    const float* r_pri, float* aggr)
{
    int wv = threadIdx.x >> 6, lane = threadIdx.x & 63;
    int i = blockIdx.x * 4 + wv;
    if (i >= n) return;
    int h = lane & 7, slot = lane >> 3;
    int hA = lane >> 3;
    int tt = ntype[i];
    float qf[16];
    load_bf8(qn + (size_t)i * ND + h * DKK, qf);
    load_bf8(qn + (size_t)i * ND + h * DKK + 8, qf + 8);
    const float* prib = r_pri + (size_t)(tt * NR * NT) * NH + h;
    int d0 = off[i], d1 = off[i + 1];
    float m = -3.0e38f, den = 0.f;
    float acc0 = 0.f, acc1 = 0.f;
    // ---- pipeline prologue: stage chunk 0 ----
    int sp_c = 0; bool live_c = false;
    uint4 ka_c, kb_c;
    ka_c.x = ka_c.y = ka_c.z = ka_c.w = 0u; kb_c = ka_c;
    if (d0 < d1) {
        int p = d0 + slot;
        live_c = (p < d1);
        sp_c = live_c ? srp[p] : 0;
        const uint4* kp = (const uint4*)(kt + (size_t)(sp_c & 0x0fffffff) * ND + h * DKK);
        ka_c = kp[0]; kb_c = kp[1];
    }
    for (int p0 = d0; p0 < d1; p0 += 8) {
        // ---- stage next chunk (loads in flight across this iteration) ----
        int np0 = p0 + 8;
        int sp_n = 0; bool live_n = false;
        uint4 ka_n, kb_n;
        ka_n.x = ka_n.y = ka_n.z = ka_n.w = 0u; kb_n = ka_n;
        if (np0 < d1) {
            int p = np0 + slot;
            live_n = (p < d1);
            sp_n = live_n ? srp[p] : 0;
            const uint4* kp = (const uint4*)(kt + (size_t)(sp_n & 0x0fffffff) * ND + h * DKK);
            ka_n = kp[0]; kb_n = kp[1];
        }
        // ---- compute current chunk ----
        int sr = sp_c & 0x0fffffff;
        int st = ((unsigned int)sp_c) >> 28;
        int r = sr & (NR - 1);
        float kf[16];
        cvt8(ka_c, kf); cvt8(kb_c, kf + 8);
        float a = 0.f;
        #pragma unroll
        for (int f = 0; f < 16; f++) a += qf[f] * kf[f];
        float pri = prib[(r * NT + st) * NH];
        float logit = fminf(fmaxf(a * pri * 0.25f, -1.0e4f), 1.0e4f);
        if (!live_c) logit = -3.0e38f;
        // early V issue: addresses depend only on sr, not on the weights
        int nlive = min(d1 - p0, 8);
        unsigned int u[8];
        #pragma unroll
        for (int s = 0; s < 8; s++) {
            int srb = __shfl(sr, s * 8 + hA, 64);
            u[s] = (s < nlive) ? *reinterpret_cast<const unsigned int*>(
                        vt + (size_t)srb * ND + lane * 2) : 0u;
        }
        float cm = logit;
        #pragma unroll
        for (int d = 8; d < 64; d <<= 1) cm = fmaxf(cm, __shfl_xor(cm, d, 64));
        float mnew = fmaxf(m, cm);
        float w = live_c ? expf(logit - mnew) : 0.f;
        float ws = w;
        #pragma unroll
        for (int d = 8; d < 64; d <<= 1) ws += __shfl_xor(ws, d, 64);
        float scale = expf(m - mnew);
        den = den * scale + ws;
        m = mnew;
        float scaleA = __shfl(scale, hA, 64);
        acc0 *= scaleA; acc1 *= scaleA;
        #pragma unroll
        for (int s = 0; s < 8; s++) {
            if (s < nlive) {
                float wb = __shfl(w, s * 8 + hA, 64);
                acc0 += wb * bf2f(u[s] & 0xffff);
                acc1 += wb * bf2f(u[s] >> 16);
            }
        }
        // ---- rotate pipeline ----
        sp_c = sp_n; live_c = live_n; ka_c = ka_n; kb_c = kb_n;
    }
    float denA = __shfl(den, hA, 64);
    float inv = 1.f / (denA + 1e-16f);
    float2 o; o.x = acc0 * inv; o.y = acc1 * inv;
    *reinterpret_cast<float2*>(aggr + (size_t)i * ND + lane * 2) = o;
}

// Fused speaker + GELU + A-projection + skip blend.
__global__ void __launch_bounds__(256) k_sfinal(
    int n, const float* x_in, const int* order, const int* tcnt, const int* tstart,
    const int* winner, const int* tgt, const ushort_t* v1b,
    const ushort_t* Wall, const float* bcat, const float* skip,
    const float* aggr, float* out)
{
    __shared__ __align__(16) float xf[32 * 132];
    __shared__ __align__(16) ushort_t xs[4096];
    __shared__ int nodes[32];
    __shared__ int wsrc[32];
    int b = blockIdx.x;
    int nb0 = (tcnt[0] + 31) >> 5, nb1 = (tcnt[1] + 31) >> 5, nb2 = (tcnt[2] + 31) >> 5;
    int t, lb;
    if (b < nb0)                  { t = 0; lb = b; }
    else if (b < nb0 + nb1)       { t = 1; lb = b - nb0; }
    else if (b < nb0 + nb1 + nb2) { t = 2; lb = b - nb0 - nb1; }
    else return;
    int segoff = lb * 32;
    int cnt = min(32, tcnt[t] - segoff);
    int segbase = tstart[t] + segoff;
    int tid = threadIdx.x;
    if (tid < 32) {
        int nd = (tid < cnt) ? order[segbase + tid] : -1;
        nodes[tid] = nd;
        int wi = (nd >= 0) ? winner[nd] : -1;
        wsrc[tid] = (wi >= 0) ? tgt[wi] : -1;
    }
    __syncthreads();
    // ---- stage A: pack speaker-source v1b rows into A-frag layout ----
    {
        int row = tid >> 3;
        int d0 = (tid & 7) * 16;
        int rt = row >> 4, rl = row & 15;
        int kb = d0 >> 5, q0 = (d0 >> 3) & 3;
        uint4 c0, c1;
        int s = (row < cnt) ? wsrc[row] : -1;
        if (s >= 0) {
            const uint4* vp = (const uint4*)(v1b + (size_t)s * ND + d0);
            c0 = vp[0]; c1 = vp[1];
        } else { c0.x = c0.y = c0.z = c0.w = 0u; c1 = c0; }
        *(uint4*)&xs[((rt * 4 + kb) * 64 + q0 * 16 + rl) * 8]       = c0;
        *(uint4*)&xs[((rt * 4 + kb) * 64 + (q0 + 1) * 16 + rl) * 8] = c1;
    }
    __syncthreads();
    int w = tid >> 6, lane = tid & 63;
    int rt = w & 1;
    // ---- stage B: spk = v1b-rows @ s2u ; g = gelu(aggr + spk) -> xf ----
    {
        bf16x8 afr[4];
        #pragma unroll
        for (int kb = 0; kb < 4; kb++)
            afr[kb] = as_bf16x8(*(const uint4*)&xs[((rt * 4 + kb) * 64 + lane) * 8]);
        for (int ct = (w >> 1); ct < 8; ct += 2) {
            const uint4* bp = (const uint4*)(Wall + (((size_t)11 * 8 + ct) * 4) * 512); // t=0, m=11
            f32x4 acc = {0.f, 0.f, 0.f, 0.f};
            #pragma unroll
            for (int kb = 0; kb < 4; kb++) {
                bf16x8 bfr = as_bf16x8(bp[kb * 64 + lane]);
                acc = __builtin_amdgcn_mfma_f32_16x16x32_bf16(afr[kb], bfr, acc, 0, 0, 0);
            }
            int col = ct * 16 + (lane & 15);
            int rbase = rt * 16 + (lane >> 4) * 4;
            #pragma unroll
            for (int r = 0; r < 4; r++) {
                int grow = rbase + r;
                if (grow >= cnt) continue;
                int node = nodes[grow];
                float g = aggr[(size_t)node * ND + col] + acc[r];
                g = 0.5f * g * (1.f + erff(g * 0.70710678118f));
                xf[grow * 132 + col] = g;
            }
        }
    }
    __syncthreads();
    // ---- stage C: repack gelu'd tile into A-frag layout ----
    {
        int row = tid >> 3;
        int d0 = (tid & 7) * 16;
        int rt2 = row >> 4, rl = row & 15;
        int kb = d0 >> 5, q0 = (d0 >> 3) & 3;
        uint4 c0, c1;
        if (row < cnt) {
            const float4* xp4 = (const float4*)(xf + row * 132 + d0);
            float4 a = xp4[0], b2 = xp4[1], c2 = xp4[2], d4 = xp4[3];
            c0.x = pk2(a.x, a.y);   c0.y = pk2(a.z, a.w);
            c0.z = pk2(b2.x, b2.y); c0.w = pk2(b2.z, b2.w);
            c1.x = pk2(c2.x, c2.y); c1.y = pk2(c2.z, c2.w);
            c1.z = pk2(d4.x, d4.y); c1.w = pk2(d4.z, d4.w);
        } else {
            c0.x = c0.y = c0.z = c0.w = 0u;
            c1 = c0;
        }
        *(uint4*)&xs[((rt2 * 4 + kb) * 64 + q0 * 16 + rl) * 8]       = c0;
        *(uint4*)&xs[((rt2 * 4 + kb) * 64 + (q0 + 1) * 16 + rl) * 8] = c1;
    }
    __syncthreads();
    // ---- stage D: out = (g @ Aw[t] + Ab[t]) * alpha + x_in * (1-alpha) ----
    float alpha = 1.f / (1.f + expf(-skip[t]));
    {
        bf16x8 afr[4];
        #pragma unroll
        for (int kb = 0; kb < 4; kb++)
            afr[kb] = as_bf16x8(*(const uint4*)&xs[((rt * 4 + kb) * 64 + lane) * 8]);
        for (int ct = (w >> 1); ct < 8; ct += 2) {
            const uint4* bp = (const uint4*)(Wall + ((((size_t)t * NMAT + 10) * 8 + ct) * 4) * 512);
            f32x4 acc = {0.f, 0.f, 0.f, 0.f};
            #pragma unroll
            for (int kb = 0; kb < 4; kb++) {
                bf16x8 bfr = as_bf16x8(bp[kb * 64 + lane]);
                acc = __builtin_amdgcn_mfma_f32_16x16x32_bf16(afr[kb], bfr, acc, 0, 0, 0);
            }
            int col = ct * 16 + (lane & 15);
            float bias = bcat[(t * NMAT + 10) * ND + col];
            int rbase = rt * 16 + (lane >> 4) * 4;
            #pragma unroll
            for (int r = 0; r < 4; r++) {
                int grow = rbase + r;
                if (grow >= cnt) continue;
                int node = nodes[grow];
                float xin = x_in[(size_t)node * ND + col];
                out[(size_t)node * ND + col] = (acc[r] + bias) * alpha + xin * (1.f - alpha);
            }
        }
    }
}

// Tier-B: fused logits + online segment softmax, wave per target node.
__global__ void __launch_bounds__(256) k_attmd(
    int n, const int* off, const int* srp, const int* ntype,
    const ushort_t* qn, const ushort_t* kt, const float* r_pri,
    float* atts, ushort_t* mb, float* db)
{
    int wv = threadIdx.x >> 6, lane = threadIdx.x & 63;
    int i = blockIdx.x * 4 + wv;
    if (i >= n) return;
    int h = lane & 7, slot = lane >> 3;
    int tt = ntype[i];
    float qf[16];
    load_bf8(qn + (size_t)i * ND + h * DKK, qf);
    load_bf8(qn + (size_t)i * ND + h * DKK + 8, qf + 8);
    const float* prib = r_pri + (size_t)(tt * NR * NT) * NH + h;
    int d0 = off[i], d1 = off[i + 1];
    float m = -3.0e38f, den = 0.f;
    #pragma unroll 2
    for (int p0 = d0; p0 < d1; p0 += 8) {
        int p = p0 + slot;
        bool live = (p < d1);
        int sp = live ? srp[p] : 0;
        int sr = sp & 0x0fffffff;
        int st = ((unsigned int)sp) >> 28;
        int r = sr & (NR - 1);
        float kf[16];
        const ushort_t* kp = kt + (size_t)sr * ND + h * DKK;
        load_bf8(kp, kf);
        load_bf8(kp + 8, kf + 8);
        float a = 0.f;
        #pragma unroll
        for (int f = 0; f < 16; f++) a += qf[f] * kf[f];
        float pri = prib[(r * NT + st) * NH];
        float logit = fminf(fmaxf(a * pri * 0.25f, -1.0e4f), 1.0e4f);
        if (live) {
            atts[(size_t)p * NH + h] = logit;
            float mnew = fmaxf(m, logit);
            den = den * expf(m - mnew) + expf(logit - mnew);
            m = mnew;
        }
    }
    #pragma unroll
    for (int d = 8; d < 64; d <<= 1) {
        float mo = __shfl_xor(m, d, 64);
        float dn = __shfl_xor(den, d, 64);
        float mnew = fmaxf(m, mo);
        den = den * expf(m - mnew) + dn * expf(mo - mnew);
        m = mnew;
    }
    if (slot == 0) {
        ushort_t mh = (d1 > d0) ? f2bf(m) : (ushort_t)0;
        float dfin = (d1 > d0) ? den * expf(m - bf2f(mh)) : 0.f;
        mb[i * NH + h] = mh;
        db[i * NH + h] = dfin;
    }
}

// Tier-B: wave-per-node aggregation; softmax normalize folded in
__global__ void __launch_bounds__(256) k_aggr_fast(
    int n, const int* off, const int* srp, const ushort_t* vt, const float* atts,
    const ushort_t* mb, const float* db, float* aggr)
{
    int wv = threadIdx.x >> 6, lane = threadIdx.x & 63;
    int i = blockIdx.x * 4 + wv;
    if (i >= n) return;
    int h = lane >> 3;
    float mref = bf2f(mb[i * NH + h]);
    float inv = 1.f / (db[i * NH + h] + 1e-16f);
    int d0 = off[i], d1 = off[i + 1];
    float acc0 = 0.f, acc1 = 0.f;
    #pragma unroll 4
    for (int p = d0; p < d1; p++) {
        int sr = srp[p] & 0x0fffffff;
        float w = expf(atts[(size_t)p * NH + h] - mref) * inv;
        unsigned int u = *reinterpret_cast<const unsigned int*>(
            vt + (size_t)sr * ND + lane * 2);
        acc0 += w * bf2f(u & 0xffff);
        acc1 += w * bf2f(u >> 16);
    }
    float2 o; o.x = acc0; o.y = acc1;
    *reinterpret_cast<float2*>(aggr + (size_t)i * ND + lane * 2) = o;
}

// ================= FALLBACK PATH (proven kernels) =================

__global__ void k_proj(int n, const float* x_in, const int* ntype, const int* order,
                       const float* Kw, const float* Kb,
                       const float* Qw, const float* Qb,
                       const float* Vw, const float* Vb,
                       ushort_t* kn, ushort_t* qn, ushort_t* vn, ushort_t* v1) {
    __shared__ float xs[NB][ND];
    __shared__ int nodes[NB];
    __shared__ int types[NB];
    int tid = threadIdx.x;
    int base = blockIdx.x * NB;
    int cnt = min(NB, n - base);
    if (tid < cnt) { int nd = order[base + tid]; nodes[tid] = nd; types[tid] = ntype[nd]; }
    __syncthreads();
    for (int j = 0; j < cnt; j++) xs[j][tid] = x_in[(size_t)nodes[j] * ND + tid];
    __syncthreads();
    bool uni = (types[0] == types[cnt - 1]);
    for (int m = 0; m < 4; m++) {
        const float *W, *B; ushort_t* out; int forced_t = -1;
        if (m == 0)      { W = Kw; B = Kb; out = kn; }
        else if (m == 1) { W = Qw; B = Qb; out = qn; }
        else if (m == 2) { W = Vw; B = Vb; out = vn; }
        else             { W = Vw; B = Vb; out = v1; forced_t = 1; }
        if (uni || forced_t >= 0) {
            int t = (forced_t >= 0) ? forced_t : types[0];
            float bias = B[t * ND + tid];
            float acc[NB];
            #pragma unroll
            for (int j = 0; j < NB; j++) acc[j] = bias;
            const float* Wp = W + (size_t)t * ND * ND + tid;
            for (int d = 0; d < ND; d++) {
                float w = Wp[(size_t)d * ND];
                #pragma unroll
                for (int j = 0; j < NB; j++) acc[j] += xs[j][d] * w;
            }
            for (int j = 0; j < cnt; j++) out[(size_t)nodes[j] * ND + tid] = f2bf(acc[j]);
        } else {
            for (int j = 0; j < cnt; j++) {
                int t = types[j];
                float acc = B[t * ND + tid];
                const float* Wp = W + (size_t)t * ND * ND + tid;
                for (int d = 0; d < ND; d++) acc += xs[j][d] * Wp[(size_t)d * ND];
                out[(size_t)nodes[j] * ND + tid] = f2bf(acc);
            }
        }
    }
}

__global__ void k_att(int e, const int* src, const int* tgt, const int* etype, const int* ntype,
                      const ushort_t* kn, const ushort_t* qn,
                      const float* r_att, const float* r_pri, float* att) {
    int id = blockIdx.x * 256 + threadIdx.x;
    if (id >= e * NH) return;
    int ee = id >> 3, h = id & 7;
    int s = src[ee], t = tgt[ee], r = etype[ee];
    float kf[16], qf[16];
    load_bf8(kn + (size_t)s * ND + h * DKK, kf);
    load_bf8(kn + (size_t)s * ND + h * DKK + 8, kf + 8);
    load_bf8(qn + (size_t)t * ND + h * DKK, qf);
    load_bf8(qn + (size_t)t * ND + h * DKK + 8, qf + 8);
    const float* W = r_att + (size_t)(r * NH + h) * DKK * DKK;
    float kt[16];
    #pragma unroll
    for (int f = 0; f < 16; f++) kt[f] = 0.f;
    #pragma unroll 4
    for (int d = 0; d < 16; d++) {
        float kd = kf[d];
        #pragma unroll
        for (int f = 0; f < 16; f++) kt[f] += kd * W[d * 16 + f];
    }
    float a = 0.f;
    #pragma unroll
    for (int f = 0; f < 16; f++) a += qf[f] * kt[f];
    int tt = ntype[t], st = ntype[s];
    float pri = r_pri[((tt * NR + r) * NT + st) * NH + h];
    float logit = a * pri * 0.25f;
    logit = fminf(fmaxf(logit, -1.0e4f), 1.0e4f);
    att[(size_t)ee * NH + h] = logit;
}

__global__ void k_mden(int n, const int* off, const int* sorted,
                       const float* att, ushort_t* mb, float* db) {
    int id = blockIdx.x * 256 + threadIdx.x;
    if (id >= n * NH) return;
    int i = id >> 3, h = id & 7;
    int d0 = off[i], d1 = off[i + 1];
    float m = -3.0e38f;
    for (int p = d0; p < d1; p++) m = fmaxf(m, att[(size_t)sorted[p] * NH + h]);
    ushort_t mh = (d1 > d0) ? f2bf(m) : (ushort_t)0;
    float mref = bf2f(mh);
    float den = 0.f;
    for (int p = d0; p < d1; p++) den += expf(att[(size_t)sorted[p] * NH + h] - mref);
    mb[id] = mh;
    db[id] = den;
}

__global__ void k_norm(int e, const int* tgt, const ushort_t* mb, const float* db, float* att) {
    int id = blockIdx.x * 256 + threadIdx.x;
    if (id >= e * NH) return;
    int ee = id >> 3, h = id & 7;
    int t = tgt[ee];
    float w = expf(att[id] - bf2f(mb[t * NH + h])) / (db[t * NH + h] + 1e-16f);
    att[id] = w;
}

__global__ void k_aggr(int n, const int* off, const int* sorted, const int* src, const int* etype,
                       const ushort_t* vn, const float* r_msg, const float* att, float* aggr) {
    int wv = threadIdx.x >> 6, lane = threadIdx.x & 63;
    int i = blockIdx.x * 4 + wv;
    if (i >= n) return;
    int h = lane >> 3, f0 = (lane & 7) * 2;
    int d0 = off[i], d1 = off[i + 1];
    float acc0 = 0.f, acc1 = 0.f;
    for (int p = d0; p < d1; p++) {
        int ee = sorted[p];
        int s = src[ee], r = etype[ee];
        float w = att[(size_t)ee * NH + h];
        float vj[16];
        load_bf8(vn + (size_t)s * ND + h * DKK, vj);
        load_bf8(vn + (size_t)s * ND + h * DKK + 8, vj + 8);
        const float* Wm = r_msg + (size_t)(r * NH + h) * DKK * DKK + f0;
        float a0 = 0.f, a1 = 0.f;
        #pragma unroll
        for (int d = 0; d < 16; d++) {
            a0 += vj[d] * Wm[d * 16];
            a1 += vj[d] * Wm[d * 16 + 1];
        }
        acc0 += w * a0; acc1 += w * a1;
    }
    aggr[(size_t)i * ND + h * DKK + f0]     = acc0;
    aggr[(size_t)i * ND + h * DKK + f0 + 1] = acc1;
}

__global__ void k_spk(int n, const int* winner, const int* tgt, const ushort_t* v1,
                      const float* s2u, float* aggr) {
    __shared__ float xs[NB][ND];
    __shared__ int wn[NB];
    int tid = threadIdx.x;
    int base = blockIdx.x * NB;
    int cnt = min(NB, n - base);
    if (tid < cnt) wn[tid] = winner[base + tid];
    __syncthreads();
    for (int j = 0; j < cnt; j++) {
        int w = wn[j];
        xs[j][tid] = (w >= 0) ? bf2f(v1[(size_t)tgt[w] * ND + tid]) : 0.f;
    }
    __syncthreads();
    float acc[NB];
    #pragma unroll
    for (int j = 0; j < NB; j++) acc[j] = 0.f;
    const float* Wp = s2u + tid;
    for (int d = 0; d < ND; d++) {
        float w = Wp[(size_t)d * ND];
        #pragma unroll
        for (int j = 0; j < NB; j++) acc[j] += xs[j][d] * w;
    }
    for (int j = 0; j < cnt; j++) {
        size_t idx = (size_t)(base + j) * ND + tid;
        float g = aggr[idx] + acc[j];
        g = 0.5f * g * (1.f + erff(g * 0.70710678118f));
        aggr[idx] = g;
    }
}

__global__ void k_final(int n, const float* x_in, const int* ntype, const int* order,
                        const float* Aw, const float* Ab, const float* skip,
                        const float* aggr, float* out) {
    __shared__ float xs[NB][ND];
    __shared__ int nodes[NB];
    __shared__ int types[NB];
    int tid = threadIdx.x;
    int base = blockIdx.x * NB;
    int cnt = min(NB, n - base);
    if (tid < cnt) { int nd = order[base + tid]; nodes[tid] = nd; types[tid] = ntype[nd]; }
    __syncthreads();
    for (int j = 0; j < cnt; j++) xs[j][tid] = aggr[(size_t)nodes[j] * ND + tid];
    __syncthreads();
    bool uni = (types[0] == types[cnt - 1]);
    if (uni) {
        int t = types[0];
        float bias = Ab[t * ND + tid];
        float acc[NB];
        #pragma unroll
        for (int j = 0; j < NB; j++) acc[j] = bias;
        const float* Wp = Aw + (size_t)t * ND * ND + tid;
        for (int d = 0; d < ND; d++) {
            float w = Wp[(size_t)d * ND];
            #pragma unroll
            for (int j = 0; j < NB; j++) acc[j] += xs[j][d] * w;
        }
        float alpha = 1.f / (1.f + expf(-skip[t]));
        for (int j = 0; j < cnt; j++) {
            float xin = x_in[(size_t)nodes[j] * ND + tid];
            out[(size_t)nodes[j] * ND + tid] = acc[j] * alpha + xin * (1.f - alpha);
        }
    } else {
        for (int j = 0; j < cnt; j++) {
            int t = types[j];
            float acc = Ab[t * ND + tid];
            const float* Wp = Aw + (size_t)t * ND * ND + tid;
            for (int d = 0; d < ND; d++) acc += xs[j][d] * Wp[(size_t)d * ND];
            float alpha = 1.f / (1.f + expf(-skip[t]));
            float xin = x_in[(size_t)nodes[j] * ND + tid];
            out[(size_t)nodes[j] * ND + tid] = acc * alpha + xin * (1.f - alpha);
        }
    }
}

extern "C" void kernel_launch(void* const* d_in, const int* in_sizes, int n_in,
                              void* d_out, int out_size, void* d_ws, size_t ws_size,
                              hipStream_t stream) {
    const float* node_inp = (const float*)d_in[0];
    const int* node_type  = (const int*)d_in[1];
    const int* edge_index = (const int*)d_in[2];
    const int* edge_type  = (const int*)d_in[3];
    const float* Kw = (const float*)d_in[5];
    const float* Kb = (const float*)d_in[6];
    const float* Qw = (const float*)d_in[7];
    const float* Qb = (const float*)d_in[8];
    const float* Vw = (const float*)d_in[9];
    const float* Vb = (const float*)d_in[10];
    const float* Aw = (const float*)d_in[11];
    const float* Ab = (const float*)d_in[12];
    const float* r_pri = (const float*)d_in[13];
    const float* r_att = (const float*)d_in[14];
    const float* r_msg = (const float*)d_in[15];
    const float* s2u   = (const float*)d_in[16];
    const float* skip  = (const float*)d_in[17];

    int n = in_sizes[1];
    int e = in_sizes[3];
    const int* srcp = edge_index;
    const int* tgtp = edge_index + e;

    char* wsp = (char*)d_ws;
    size_t woff = 0;
    auto alloc = [&](size_t b) { void* p = wsp + woff; woff += (b + 255) & ~(size_t)255; return p; };

    // ---- common infra ----
    int* offs     = (int*)alloc((size_t)(n + 1) * 4);
    int* winner   = (int*)alloc((size_t)n * 4);
    int* order    = (int*)alloc((size_t)n * 4);
    int* tcnt     = (int*)alloc(16);
    int* tstart   = (int*)alloc(16);
    int* bsum4    = (int*)alloc(4096);
    int* boff4    = (int*)alloc(4096);
    int* eord     = (int*)alloc((size_t)e * 4);   // fast: srp record; fallback: sorted edge id
    ushort_t* mb  = (ushort_t*)alloc((size_t)n * NH * 2);
    float* db     = (float*)alloc((size_t)n * NH * 4);
    ushort_t* v1b = (ushort_t*)alloc((size_t)n * ND * 2);
    float* att    = (float*)alloc((size_t)e * NH * 4);
    size_t commonEnd = woff;

    // rank lives in att's space: written by k_count, dead after k_scatter.
    int* rank = (int*)att;

    // ---- Tier B layout ----
    woff = commonEnd;
    ushort_t* WallB = (ushort_t*)alloc((size_t)NT * NMAT * 8 * 4 * 512 * 2);
    float* bcatB    = (float*)alloc((size_t)NT * NMAT * ND * 4);
    char* F         = (char*)alloc((size_t)n * 1536);   // phase1: qn+kt; phase2: vt+aggr
    size_t fastEnd = woff;

    // ---- Tier A (flash) layout: qn+kt+vt live together; aggr overlays att ----
    woff = commonEnd;
    ushort_t* WallA = (ushort_t*)alloc((size_t)NT * NMAT * 8 * 4 * 512 * 2);
    float* bcatA    = (float*)alloc((size_t)NT * NMAT * ND * 4);
    ushort_t* qnA   = (ushort_t*)alloc((size_t)n * ND * 2);
    ushort_t* ktA   = (ushort_t*)alloc((size_t)n * NR * ND * 2);
    ushort_t* vtA   = (ushort_t*)alloc((size_t)n * NR * ND * 2);
    size_t tierAEnd = woff;
    float* aggrA = (float*)att;   // requires e*NH*4 >= n*ND*4 (equal here); rank dead by then

    int gn = (n + 255) / 256;
    int ge = (e + 255) / 256;
    int nbscan = n / SCB + 1;
    int gproj = (n + 31) / 32 + NT;

    int tierA = (ws_size >= tierAEnd) && ((size_t)e * NH >= (size_t)n * ND);
    int fast  = (ws_size >= fastEnd);

    k_zero<<<gn, 256, 0, stream>>>(n, offs, winner);
    k_count<<<ge, 256, 0, stream>>>(e, srcp, tgtp, edge_type, offs, winner, rank);
    k_scanA<<<nbscan, 256, 0, stream>>>(n, offs, node_type, bsum4);
    k_scanB<<<1, 64, 0, stream>>>(nbscan, bsum4, boff4, tcnt, tstart);
    k_scanC<<<nbscan, 256, 0, stream>>>(n, offs, node_type, boff4, tstart, order);
    k_scatter<<<ge, 256, 0, stream>>>(e, srcp, tgtp, edge_type, node_type, offs, rank,
                                      eord, (tierA || fast) ? 1 : 0);

    if (tierA) {
        // ======== TIER A: single projection + pipelined flash + fused epilogue ========
        k_pack<<<NT * NMAT * 8 * 4, 64, 0, stream>>>(Qw, Qb, Kw, Kb, Vw, Vb, Aw, Ab,
                                                     s2u, r_att, r_msg, WallA, bcatA);
        k_projall<<<gproj, 256, 0, stream>>>(n, node_inp, order, tcnt, tstart, WallA, bcatA,
                                             qnA, ktA, v1b, vtA);
        k_flash<<<(n + 3) / 4, 256, 0, stream>>>(n, offs, eord, node_type,
                                                 qnA, ktA, vtA, r_pri, aggrA);
        k_sfinal<<<gproj, 256, 0, stream>>>(n, node_inp, order, tcnt, tstart,
                                            winner, tgtp, v1b, WallA, bcatA, skip,
                                            aggrA, (float*)d_out);
    } else if (fast) {
        // ======== TIER B ========
        ushort_t* qn  = (ushort_t*)F;
        ushort_t* kt  = (ushort_t*)(F + (size_t)n * 256);
        ushort_t* vt  = (ushort_t*)F;                         // overlays qn+kt (dead after k_attmd)
        float* aggr   = (float*)(F + (size_t)n * 1024);       // overlays kt tail (dead)

        k_pack<<<NT * NMAT * 8 * 4, 64, 0, stream>>>(Qw, Qb, Kw, Kb, Vw, Vb, Aw, Ab,
                                                     s2u, r_att, r_msg, WallB, bcatB);
        k_projm<<<gproj, 256, 0, stream>>>(n, node_inp, order, tcnt, tstart, WallB, bcatB,
                                           0, 6, qn, kt, v1b, (ushort_t*)nullptr);
        k_attmd<<<(n + 3) / 4, 256, 0, stream>>>(n, offs, eord, node_type,
                                                 qn, kt, r_pri, att, mb, db);
        k_projm<<<gproj, 256, 0, stream>>>(n, node_inp, order, tcnt, tstart, WallB, bcatB,
                                           6, 4, (ushort_t*)nullptr, (ushort_t*)nullptr,
                                           (ushort_t*)nullptr, vt);
        k_aggr_fast<<<(n + 3) / 4, 256, 0, stream>>>(n, offs, eord, vt, att, mb, db, aggr);
        k_sfinal<<<gproj, 256, 0, stream>>>(n, node_inp, order, tcnt, tstart,
                                            winner, tgtp, v1b, WallB, bcatB, skip,
                                            aggr, (float*)d_out);
    } else {
        // ======== FALLBACK ========
        woff = commonEnd;
        ushort_t* vn  = (ushort_t*)alloc((size_t)n * ND * 2);
        char* regA    = (char*)alloc((size_t)n * ND * 2 * 2);
        ushort_t* kn  = (ushort_t*)regA;
        ushort_t* qn  = (ushort_t*)(regA + (size_t)n * ND * 2);
        float* aggr   = (float*)regA;

        k_proj<<<(n + NB - 1) / NB, 128, 0, stream>>>(n, node_inp, node_type, order,
                                                      Kw, Kb, Qw, Qb, Vw, Vb, kn, qn, vn, v1b);
        k_att<<<(e * NH + 255) / 256, 256, 0, stream>>>(e, srcp, tgtp, edge_type, node_type,
                                                        kn, qn, r_att, r_pri, att);
        k_mden<<<(n * NH + 255) / 256, 256, 0, stream>>>(n, offs, eord, att, mb, db);
        k_norm<<<(e * NH + 255) / 256, 256, 0, stream>>>(e, tgtp, mb, db, att);
        k_aggr<<<(n + 3) / 4, 256, 0, stream>>>(n, offs, eord, srcp, edge_type, vn, r_msg, att, aggr);
        k_spk<<<(n + NB - 1) / NB, 128, 0, stream>>>(n, winner, tgtp, v1b, s2u, aggr);
        k_final<<<(n + NB - 1) / NB, 128, 0, stream>>>(n, node_inp, node_type, order,
                                                       Aw, Ab, skip, aggr, (float*)d_out);
    }
}